// Round 1
// baseline (397.679 us; speedup 1.0000x reference)
//
#include <hip/hip_runtime.h>
#include <hip/hip_bf16.h>

#define HID 768
#define NHEADS 12
#define HDIM 64
#define SEQ 4096
#define BB 2
#define MTOT (BB * SEQ)   // 8192 rows

typedef __attribute__((ext_vector_type(8))) short bf16x8;
typedef __attribute__((ext_vector_type(16))) float f32x16;

#define LOG2E 1.4426950408889634f

__device__ inline unsigned pack2bf(float a, float b) {
    __hip_bfloat162 h = __float22bfloat162_rn(float2{a, b});
    return *(unsigned*)&h;
}

// ---------------------------------------------------------------------------
// Kernel 0a: cast X fp32 -> bf16. grid 3072, block 256, 8 elems/thread.
// ---------------------------------------------------------------------------
__global__ __launch_bounds__(256) void cast_x_kernel(
    const float* __restrict__ X, __hip_bfloat16* __restrict__ Xb)
{
    const size_t i = ((size_t)blockIdx.x * 256 + threadIdx.x) * 8;
    const float4 x0 = *(const float4*)(X + i);
    const float4 x1 = *(const float4*)(X + i + 4);
    unsigned u[4];
    u[0] = pack2bf(x0.x, x0.y);
    u[1] = pack2bf(x0.z, x0.w);
    u[2] = pack2bf(x1.x, x1.y);
    u[3] = pack2bf(x1.z, x1.w);
    *(uint4*)(Xb + i) = *(uint4*)u;
}

// ---------------------------------------------------------------------------
// Kernel 0b: pack weights: W[in][out] fp32 -> Wt[out(global)][in] bf16.
// z=0..3 selects Wq,Wk,Wv,Wo; Wo at row offset 2304.
// ---------------------------------------------------------------------------
__global__ __launch_bounds__(256) void pack_w_kernel(
    const float* __restrict__ Wq, const float* __restrict__ Wk,
    const float* __restrict__ Wv, const float* __restrict__ Wo,
    __hip_bfloat16* __restrict__ Wt)
{
    const int z = blockIdx.z;
    const float* __restrict__ W = (z == 0) ? Wq : (z == 1) ? Wk : (z == 2) ? Wv : Wo;
    const int in0  = blockIdx.x * 64;
    const int out0 = blockIdx.y * 64;
    const int t = threadIdx.x;

    __shared__ float T[64][65];
#pragma unroll
    for (int i = 0; i < 4; ++i) {
        const int idx = t + 256 * i;
        const int row = idx >> 4;
        const int c4  = (idx & 15) << 2;
        const float4 v = *(const float4*)(W + (size_t)(in0 + row) * HID + out0 + c4);
        T[row][c4 + 0] = v.x; T[row][c4 + 1] = v.y;
        T[row][c4 + 2] = v.z; T[row][c4 + 3] = v.w;
    }
    __syncthreads();

    const int o  = t >> 2;
    const int cb = (t & 3) << 4;
    __hip_bfloat16 tmp[16];
#pragma unroll
    for (int k = 0; k < 16; ++k)
        tmp[k] = __float2bfloat16(T[cb + k][o]);
    __hip_bfloat16* __restrict__ dst =
        Wt + (size_t)(z * HID + out0 + o) * HID + in0 + cb;
    *(uint4*)(dst)     = *(uint4*)(&tmp[0]);
    *(uint4*)(dst + 8) = *(uint4*)(&tmp[8]);
}

// ---------------------------------------------------------------------------
// Kernel 1: fused QKV MFMA GEMM. Q,K -> bf16 [b,h,s,64]; V -> bf16 [b,h,64,s]
// (transposed in-epilogue via LDS). grid (18, 64), block 256, 128x128, BK=64.
// ---------------------------------------------------------------------------
__global__ __launch_bounds__(256) void qkv_mfma_kernel(
    const __hip_bfloat16* __restrict__ Xb, const __hip_bfloat16* __restrict__ Wt,
    const float* __restrict__ bq, const float* __restrict__ bk,
    const float* __restrict__ bv,
    __hip_bfloat16* __restrict__ Qo, __hip_bfloat16* __restrict__ Ko,
    __hip_bfloat16* __restrict__ Vo)
{
    const int nblk = blockIdx.x;          // 0..17
    const int z  = nblk / 6;              // 0=Q,1=K,2=V
    const int f0 = (nblk % 6) * 128;      // feature base within segment
    const int n0 = nblk * 128;            // row base in Wt
    const int m0 = blockIdx.y * 128;

    const float* __restrict__ bias = (z == 0) ? bq : (z == 1) ? bk : bv;

    const int t    = threadIdx.x;
    const int w    = t >> 6;
    const int lane = t & 63;
    const int col  = lane & 31;
    const int g    = lane >> 5;
    const int wm   = w & 1;
    const int wn   = w >> 1;

    __shared__ __hip_bfloat16 smem[2 * 128 * 72];   // As | Bs; Ts overlays both
    __hip_bfloat16 (*As)[72] = (__hip_bfloat16(*)[72])smem;
    __hip_bfloat16 (*Bs)[72] = (__hip_bfloat16(*)[72])(smem + 128 * 72);

    f32x16 acc[2][2];
#pragma unroll
    for (int mt = 0; mt < 2; ++mt)
#pragma unroll
        for (int nt = 0; nt < 2; ++nt)
#pragma unroll
            for (int r = 0; r < 16; ++r) acc[mt][nt][r] = 0.f;

    for (int k0 = 0; k0 < HID; k0 += 64) {
        __syncthreads();
#pragma unroll
        for (int i = 0; i < 4; ++i) {
            const int idx = t + 256 * i;     // 0..1023
            const int row = idx >> 3;        // 0..127
            const int c8  = (idx & 7) << 3;  // 0..56
            *(uint4*)&As[row][c8] = *(const uint4*)(Xb + (size_t)(m0 + row) * HID + k0 + c8);
            *(uint4*)&Bs[row][c8] = *(const uint4*)(Wt + (size_t)(n0 + row) * HID + k0 + c8);
        }
        __syncthreads();
#pragma unroll
        for (int kh = 0; kh < 4; ++kh) {
            const int ko = 16 * kh + 8 * g;
            const bf16x8 a0 = *(const bf16x8*)&As[64 * wm + col][ko];
            const bf16x8 a1 = *(const bf16x8*)&As[64 * wm + 32 + col][ko];
            const bf16x8 b0 = *(const bf16x8*)&Bs[64 * wn + col][ko];
            const bf16x8 b1 = *(const bf16x8*)&Bs[64 * wn + 32 + col][ko];
            acc[0][0] = __builtin_amdgcn_mfma_f32_32x32x16_bf16(a0, b0, acc[0][0], 0, 0, 0);
            acc[0][1] = __builtin_amdgcn_mfma_f32_32x32x16_bf16(a0, b1, acc[0][1], 0, 0, 0);
            acc[1][0] = __builtin_amdgcn_mfma_f32_32x32x16_bf16(a1, b0, acc[1][0], 0, 0, 0);
            acc[1][1] = __builtin_amdgcn_mfma_f32_32x32x16_bf16(a1, b1, acc[1][1], 0, 0, 0);
        }
    }

    if (z < 2) {
        __hip_bfloat16* __restrict__ Out = (z == 0) ? Qo : Ko;
        const int h = (f0 >> 6) + wn;
#pragma unroll
        for (int mt = 0; mt < 2; ++mt)
#pragma unroll
            for (int nt = 0; nt < 2; ++nt) {
                const int d = 32 * nt + col;
                const float bsv = bias[f0 + 64 * wn + d];
#pragma unroll
                for (int r = 0; r < 16; ++r) {
                    const int m = m0 + 64 * wm + 32 * mt + (r & 3) + 8 * (r >> 2) + 4 * g;
                    const int b = m >> 12;
                    const int s = m & (SEQ - 1);
                    Out[(((size_t)(b * NHEADS + h)) * SEQ + s) * HDIM + d] =
                        __float2bfloat16(acc[mt][nt][r] + bsv);
                }
            }
    } else {
        // V: transpose 128x128 tile via LDS, write Vt [bh][d][s]
        __syncthreads();   // K-loop LDS reads done before overlay
        __hip_bfloat16 (*Ts)[136] = (__hip_bfloat16(*)[136])smem;  // 34816 B
#pragma unroll
        for (int mt = 0; mt < 2; ++mt)
#pragma unroll
            for (int nt = 0; nt < 2; ++nt) {
                const int nloc = 64 * wn + 32 * nt + col;
                const float bsv = bias[f0 + nloc];
#pragma unroll
                for (int rg = 0; rg < 4; ++rg) {
                    const int mbase = 64 * wm + 32 * mt + 8 * rg + 4 * g;
                    unsigned pu[2];
                    pu[0] = pack2bf(acc[mt][nt][4 * rg + 0] + bsv,
                                    acc[mt][nt][4 * rg + 1] + bsv);
                    pu[1] = pack2bf(acc[mt][nt][4 * rg + 2] + bsv,
                                    acc[mt][nt][4 * rg + 3] + bsv);
                    *(uint2*)&Ts[nloc][mbase] = *(uint2*)pu;
                }
            }
        __syncthreads();
        const int nloc = t >> 1;
        const int half = t & 1;
        const int hh = (f0 >> 6) + (nloc >> 6);
        const int d  = nloc & 63;
        const int bb = m0 >> 12;
        const int s0 = m0 & (SEQ - 1);
        __hip_bfloat16* __restrict__ dst =
            Vo + (((size_t)(bb * NHEADS + hh)) * HDIM + d) * SEQ + s0 + 64 * half;
        const __hip_bfloat16* srcp = &Ts[nloc][64 * half];
#pragma unroll
        for (int j = 0; j < 8; ++j)
            *(uint4*)(dst + 8 * j) = *(const uint4*)(srcp + 8 * j);
    }
}

// ---------------------------------------------------------------------------
// Kernel 2: MFMA flash attention (S^T-swap + permlane P-transform, K-split).
// exp2-folded softmax, no clamp. launch_bounds(256,2): unified VGPR+acc
// footprint (~200 regs with the T14 pipeline) fits 2 waves/SIMD; (256,4)
// spilled accumulators to scratch (12x regression, earlier session).
// Round-1 changes vs 328us baseline:
//  - T14 async-STAGE: next K/V tile global loads issued into regs right
//    after the LDS-ready barrier; ds_write at top of next iteration
//    (HBM latency hides under QK/softmax/PV compute).
//  - whole-kspan madd precomputed once into LDS (removes per-tile mask
//    staging; mm float4 reads hoisted out of the mt loop: 16->8 b128/tile).
//  - PV loop interchanged (kh outer): bv0/bv1 read once for both mt
//    (16->8 b128/tile).
//  - P-transform via v_permlane32_swap_b32 (2 per kh*mt) replacing
//    2 ds_bpermute + divergent selects (T12 primitive, m255: 1.20x).
// ---------------------------------------------------------------------------
typedef __attribute__((ext_vector_type(2))) unsigned uswap2;

__global__ __launch_bounds__(256, 2) void attn_kernel(
    const __hip_bfloat16* __restrict__ Qb, const __hip_bfloat16* __restrict__ Kb,
    const __hip_bfloat16* __restrict__ Vt, const float* __restrict__ mask,
    __hip_bfloat16* __restrict__ Op, float* __restrict__ lp)
{
    const int bh = blockIdx.y;
    const int b  = bh / NHEADS;
    const int h  = bh - b * NHEADS;
    const int kspan = SEQ / gridDim.z;
    const int kbeg  = blockIdx.z * kspan;

    const int t    = threadIdx.x;
    const int w    = t >> 6;
    const int lane = t & 63;
    const int col  = lane & 31;
    const int g    = lane >> 5;
    const int qw   = blockIdx.x * 256 + 64 * w;

    __shared__ __hip_bfloat16 Ks[64][72];
    __shared__ __hip_bfloat16 Vts[64][72];
    __shared__ float madd[2048];   // whole kspan (max SEQ/2), premult by log2(e)

    const __hip_bfloat16* __restrict__ Qh = Qb + (size_t)bh * SEQ * HDIM;
    const __hip_bfloat16* __restrict__ Kh = Kb + (size_t)bh * SEQ * HDIM;
    const __hip_bfloat16* __restrict__ Vh = Vt + (size_t)bh * HDIM * SEQ;

    // whole-span additive mask, computed once
    for (int j = t; j < kspan; j += 256)
        madd[j] = (1.0f - mask[b * SEQ + kbeg + j]) * (-10000.0f * LOG2E);

    bf16x8 bq[2][4];
#pragma unroll
    for (int mt = 0; mt < 2; ++mt)
#pragma unroll
        for (int kh = 0; kh < 4; ++kh)
            bq[mt][kh] = *(const bf16x8*)(Qh + (size_t)(qw + 32 * mt + col) * HDIM
                                          + 16 * kh + 8 * g);

    f32x16 O[2][2];
    float lac[2] = {0.f, 0.f};
#pragma unroll
    for (int mt = 0; mt < 2; ++mt)
#pragma unroll
        for (int dt = 0; dt < 2; ++dt)
#pragma unroll
            for (int r = 0; r < 16; ++r) O[mt][dt][r] = 0.f;

    const float kscale = 0.125f * LOG2E;

    // --- T14 staging pipeline: global -> regs (early) -> LDS (late) ---
    const int srow = t >> 3;          // 0..31
    const int sc8  = (t & 7) << 3;    // 0..56
    uint4 kreg[2], vreg[2];

#define ATTN_LOAD(KT)                                                          \
    kreg[0] = *(const uint4*)(Kh + (size_t)((KT) + srow) * HDIM + sc8);        \
    kreg[1] = *(const uint4*)(Kh + (size_t)((KT) + srow + 32) * HDIM + sc8);   \
    vreg[0] = *(const uint4*)(Vh + (size_t)srow * SEQ + (KT) + sc8);           \
    vreg[1] = *(const uint4*)(Vh + (size_t)(srow + 32) * SEQ + (KT) + sc8);

    ATTN_LOAD(kbeg);

    for (int kt0 = 0; kt0 < kspan; kt0 += 64) {
        __syncthreads();               // prev tile's LDS reads done (all waves)
        *(uint4*)&Ks[srow][sc8]       = kreg[0];
        *(uint4*)&Ks[srow + 32][sc8]  = kreg[1];
        *(uint4*)&Vts[srow][sc8]      = vreg[0];
        *(uint4*)&Vts[srow + 32][sc8] = vreg[1];
        __syncthreads();               // tile ready
        if (kt0 + 64 < kspan) { ATTN_LOAD(kbeg + kt0 + 64); }  // in flight during compute

        // ---- QK^T (swapped: St[k][q]) ----
        f32x16 St[2][2];
#pragma unroll
        for (int mt = 0; mt < 2; ++mt)
#pragma unroll
            for (int nt = 0; nt < 2; ++nt)
#pragma unroll
                for (int r = 0; r < 16; ++r) St[mt][nt][r] = 0.f;

#pragma unroll
        for (int kh = 0; kh < 4; ++kh) {
            const bf16x8 ak0 = *(const bf16x8*)&Ks[col][16 * kh + 8 * g];
            const bf16x8 ak1 = *(const bf16x8*)&Ks[32 + col][16 * kh + 8 * g];
            St[0][0] = __builtin_amdgcn_mfma_f32_32x32x16_bf16(ak0, bq[0][kh], St[0][0], 0, 0, 0);
            St[1][0] = __builtin_amdgcn_mfma_f32_32x32x16_bf16(ak0, bq[1][kh], St[1][0], 0, 0, 0);
            St[0][1] = __builtin_amdgcn_mfma_f32_32x32x16_bf16(ak1, bq[0][kh], St[0][1], 0, 0, 0);
            St[1][1] = __builtin_amdgcn_mfma_f32_32x32x16_bf16(ak1, bq[1][kh], St[1][1], 0, 0, 0);
        }

        // ---- softmax exp + pack (mm hoisted across mt) ----
        unsigned pkx[2][2][4], pky[2][2][4];   // [mt][nt][b4]
#pragma unroll
        for (int nt = 0; nt < 2; ++nt)
#pragma unroll
            for (int b4 = 0; b4 < 4; ++b4) {
                const float4 mm = *(const float4*)&madd[kt0 + 32 * nt + 8 * b4 + 4 * g];
#pragma unroll
                for (int mt = 0; mt < 2; ++mt) {
                    const float p0 = __builtin_amdgcn_exp2f(fmaf(St[mt][nt][4 * b4 + 0], kscale, mm.x));
                    const float p1 = __builtin_amdgcn_exp2f(fmaf(St[mt][nt][4 * b4 + 1], kscale, mm.y));
                    const float p2 = __builtin_amdgcn_exp2f(fmaf(St[mt][nt][4 * b4 + 2], kscale, mm.z));
                    const float p3 = __builtin_amdgcn_exp2f(fmaf(St[mt][nt][4 * b4 + 3], kscale, mm.w));
                    lac[mt] += (p0 + p1) + (p2 + p3);
                    pkx[mt][nt][b4] = pack2bf(p0, p1);
                    pky[mt][nt][b4] = pack2bf(p2, p3);
                }
            }

        // ---- PV (kh outer: bv shared across mt; permlane32_swap transform) ----
#pragma unroll
        for (int kh = 0; kh < 4; ++kh) {
            const int nt  = kh >> 1;
            const int khl = kh & 1;
            const bf16x8 bv0 = *(const bf16x8*)&Vts[col][16 * kh + 8 * g];
            const bf16x8 bv1 = *(const bf16x8*)&Vts[32 + col][16 * kh + 8 * g];
#pragma unroll
            for (int mt = 0; mt < 2; ++mt) {
                union { unsigned u[4]; bf16x8 v; } au;
#if __has_builtin(__builtin_amdgcn_permlane32_swap)
                // swap(vdst=lo, src=hi): vdst[32..63] <-> src[0..31]
                // result: {new_lo, new_hi}; lanes g=0 keep lo / get partner lo,
                // lanes g=1 get partner hi / keep hi -> exactly the A-frag order.
                uswap2 sx = __builtin_amdgcn_permlane32_swap(
                    pkx[mt][nt][2 * khl], pkx[mt][nt][2 * khl + 1], false, false);
                uswap2 sy = __builtin_amdgcn_permlane32_swap(
                    pky[mt][nt][2 * khl], pky[mt][nt][2 * khl + 1], false, false);
                au.u[0] = sx[0]; au.u[1] = sy[0]; au.u[2] = sx[1]; au.u[3] = sy[1];
#else
                const unsigned lo_x = pkx[mt][nt][2 * khl],     lo_y = pky[mt][nt][2 * khl];
                const unsigned hi_x = pkx[mt][nt][2 * khl + 1], hi_y = pky[mt][nt][2 * khl + 1];
                const unsigned sxv = g ? lo_x : hi_x;
                const unsigned syv = g ? lo_y : hi_y;
                const unsigned rx = (unsigned)__shfl_xor((int)sxv, 32, 64);
                const unsigned ry = (unsigned)__shfl_xor((int)syv, 32, 64);
                if (g) { au.u[0] = rx; au.u[1] = ry; au.u[2] = hi_x; au.u[3] = hi_y; }
                else   { au.u[0] = lo_x; au.u[1] = lo_y; au.u[2] = rx; au.u[3] = ry; }
#endif
                O[mt][0] = __builtin_amdgcn_mfma_f32_32x32x16_bf16(au.v, bv0, O[mt][0], 0, 0, 0);
                O[mt][1] = __builtin_amdgcn_mfma_f32_32x32x16_bf16(au.v, bv1, O[mt][1], 0, 0, 0);
            }
        }
    }
#undef ATTN_LOAD

    const size_t opbase = (size_t)blockIdx.z * ((size_t)MTOT * HID);
#pragma unroll
    for (int mt = 0; mt < 2; ++mt) {
        const float l = lac[mt] + __shfl_xor(lac[mt], 32, 64);
        if (g == 0)
            lp[((size_t)blockIdx.z * (BB * NHEADS) + bh) * SEQ + qw + 32 * mt + col] = l;
#pragma unroll
        for (int dt = 0; dt < 2; ++dt)
#pragma unroll
            for (int r = 0; r < 16; ++r) {
                const int q = qw + 32 * mt + (r & 3) + 8 * (r >> 2) + 4 * g;
                const int d = 32 * dt + col;
                Op[opbase + ((size_t)b * SEQ + q) * HID + h * HDIM + d] =
                    __float2bfloat16(O[mt][dt][r]);
            }
    }
}

// ---------------------------------------------------------------------------
// Kernel 2b: combine K-split partials -> Ctx bf16. 8 elems/thread.
// ---------------------------------------------------------------------------
__global__ __launch_bounds__(256) void combine_kernel(
    const __hip_bfloat16* __restrict__ Op, const float* __restrict__ lp,
    __hip_bfloat16* __restrict__ Ctx, int KS)
{
    const size_t i = ((size_t)blockIdx.x * 256 + threadIdx.x) * 8;
    const int n   = (int)(i % HID);
    const int row = (int)(i / HID);
    const int h = n >> 6;
    const int b = row >> 12;
    const int q = row & (SEQ - 1);
    const int bh = b * NHEADS + h;

    float denom = 0.f;
    float o[8] = {};
    for (int kz = 0; kz < KS; ++kz) {
        denom += lp[((size_t)kz * (BB * NHEADS) + bh) * SEQ + q];
        uint4 u = *(const uint4*)(Op + (size_t)kz * ((size_t)MTOT * HID) + i);
        const __hip_bfloat16* e = (const __hip_bfloat16*)&u;
#pragma unroll
        for (int j = 0; j < 8; ++j) o[j] += __bfloat162float(e[j]);
    }
    const float inv = 1.0f / denom;
    unsigned u[4];
#pragma unroll
    for (int j = 0; j < 4; ++j)
        u[j] = pack2bf(o[2 * j] * inv, o[2 * j + 1] * inv);
    *(uint4*)(Ctx + i) = *(uint4*)u;
}

// ---------------------------------------------------------------------------
// Kernel 3: output projection MFMA + bias + residual -> Resid fp32.
// grid (6, 64), block 256.
// ---------------------------------------------------------------------------
__global__ __launch_bounds__(256) void out_mfma_kernel(
    const __hip_bfloat16* __restrict__ Cb, const __hip_bfloat16* __restrict__ Wto,
    const float* __restrict__ bo, const float* __restrict__ X,
    float* __restrict__ Resid)
{
    const int n0 = blockIdx.x * 128;
    const int m0 = blockIdx.y * 128;

    const int t    = threadIdx.x;
    const int w    = t >> 6;
    const int lane = t & 63;
    const int col  = lane & 31;
    const int g    = lane >> 5;
    const int wm   = w & 1;
    const int wn   = w >> 1;

    __shared__ __hip_bfloat16 As[128][72];
    __shared__ __hip_bfloat16 Bs[128][72];

    f32x16 acc[2][2];
#pragma unroll
    for (int mt = 0; mt < 2; ++mt)
#pragma unroll
        for (int nt = 0; nt < 2; ++nt)
#pragma unroll
            for (int r = 0; r < 16; ++r) acc[mt][nt][r] = 0.f;

    for (int k0 = 0; k0 < HID; k0 += 64) {
        __syncthreads();
#pragma unroll
        for (int i = 0; i < 4; ++i) {
            const int idx = t + 256 * i;
            const int row = idx >> 3;
            const int c8  = (idx & 7) << 3;
            *(uint4*)&As[row][c8] = *(const uint4*)(Cb  + (size_t)(m0 + row) * HID + k0 + c8);
            *(uint4*)&Bs[row][c8] = *(const uint4*)(Wto + (size_t)(n0 + row) * HID + k0 + c8);
        }
        __syncthreads();
#pragma unroll
        for (int kh = 0; kh < 4; ++kh) {
            const int ko = 16 * kh + 8 * g;
            const bf16x8 a0 = *(const bf16x8*)&As[64 * wm + col][ko];
            const bf16x8 a1 = *(const bf16x8*)&As[64 * wm + 32 + col][ko];
            const bf16x8 b0 = *(const bf16x8*)&Bs[64 * wn + col][ko];
            const bf16x8 b1 = *(const bf16x8*)&Bs[64 * wn + 32 + col][ko];
            acc[0][0] = __builtin_amdgcn_mfma_f32_32x32x16_bf16(a0, b0, acc[0][0], 0, 0, 0);
            acc[0][1] = __builtin_amdgcn_mfma_f32_32x32x16_bf16(a0, b1, acc[0][1], 0, 0, 0);
            acc[1][0] = __builtin_amdgcn_mfma_f32_32x32x16_bf16(a1, b0, acc[1][0], 0, 0, 0);
            acc[1][1] = __builtin_amdgcn_mfma_f32_32x32x16_bf16(a1, b1, acc[1][1], 0, 0, 0);
        }
    }

#pragma unroll
    for (int mt = 0; mt < 2; ++mt)
#pragma unroll
        for (int nt = 0; nt < 2; ++nt) {
            const int n = n0 + 64 * wn + 32 * nt + col;
            const float bsv = bo[n];
#pragma unroll
            for (int r = 0; r < 16; ++r) {
                const int m = m0 + 64 * wm + 32 * mt + (r & 3) + 8 * (r >> 2) + 4 * g;
                Resid[(size_t)m * HID + n] = acc[mt][nt][r] + bsv + X[(size_t)m * HID + n];
            }
        }
}

// ---------------------------------------------------------------------------
// Kernel 4: LayerNorm.
// ---------------------------------------------------------------------------
__global__ __launch_bounds__(256) void ln_kernel(
    const float* __restrict__ Rin, const float* __restrict__ gamma,
    const float* __restrict__ beta, float* __restrict__ Out)
{
    const int row = blockIdx.x;
    const int t   = threadIdx.x;
    const float* __restrict__ x = Rin + (size_t)row * HID;

    const float v0 = x[t];
    const float v1 = x[t + 256];
    const float v2 = x[t + 512];
    float s  = v0 + v1 + v2;
    float s2 = v0 * v0 + v1 * v1 + v2 * v2;
#pragma unroll
    for (int off = 32; off; off >>= 1) {
        s  += __shfl_xor(s,  off, 64);
        s2 += __shfl_xor(s2, off, 64);
    }
    __shared__ float rs[4], rs2[4];
    const int w = t >> 6, lane = t & 63;
    if (lane == 0) { rs[w] = s; rs2[w] = s2; }
    __syncthreads();
    const float tot  = rs[0] + rs[1] + rs[2] + rs[3];
    const float tot2 = rs2[0] + rs2[1] + rs2[2] + rs2[3];
    const float mu   = tot * (1.0f / HID);
    const float var  = tot2 * (1.0f / HID) - mu * mu;
    const float rsig = rsqrtf(var + 1e-5f);

    float* __restrict__ y = Out + (size_t)row * HID;
    y[t]       = (v0 - mu) * rsig * gamma[t]       + beta[t];
    y[t + 256] = (v1 - mu) * rsig * gamma[t + 256] + beta[t + 256];
    y[t + 512] = (v2 - mu) * rsig * gamma[t + 512] + beta[t + 512];
}

// ---------------------------------------------------------------------------
extern "C" void kernel_launch(void* const* d_in, const int* in_sizes, int n_in,
                              void* d_out, int out_size, void* d_ws, size_t ws_size,
                              hipStream_t stream)
{
    const float* X     = (const float*)d_in[0];
    const float* mask  = (const float*)d_in[1];
    const float* Wq    = (const float*)d_in[2];
    const float* bq    = (const float*)d_in[3];
    const float* Wk    = (const float*)d_in[4];
    const float* bk    = (const float*)d_in[5];
    const float* Wv    = (const float*)d_in[6];
    const float* bv    = (const float*)d_in[7];
    const float* Wo    = (const float*)d_in[8];
    const float* bo    = (const float*)d_in[9];
    const float* gamma = (const float*)d_in[10];
    const float* beta  = (const float*)d_in[11];
    float* out = (float*)d_out;

    const size_t N = (size_t)MTOT * HID;        // 6,291,456 elements
    const size_t WTE = (size_t)4 * HID * HID;

    char* p = (char*)d_ws;
    __hip_bfloat16* Xb  = (__hip_bfloat16*)p;  p += 2 * N;
    __hip_bfloat16* Wt  = (__hip_bfloat16*)p;  p += 2 * WTE;
    __hip_bfloat16* Qw  = (__hip_bfloat16*)p;  p += 2 * N;
    __hip_bfloat16* Kw  = (__hip_bfloat16*)p;  p += 2 * N;
    __hip_bfloat16* Vtw = (__hip_bfloat16*)p;  p += 2 * N;
    char* opb = p;
    const size_t fixed = (size_t)(opb - (char*)d_ws);

    const size_t lpsz4 = 4 * (size_t)(BB * NHEADS) * SEQ * sizeof(float);
    const int KS = (ws_size >= fixed + 4 * 2 * N + lpsz4) ? 4 : 2;

    __hip_bfloat16* Op  = (__hip_bfloat16*)opb;          // KS*N bf16 partial O
    float* lpt = (float*)(opb + (size_t)KS * 2 * N);     // KS*24*SEQ fp32
    __hip_bfloat16* Ctxb = Xb;      // Xb dead after qkv
    float* Rd = (float*)Kw;         // Kw+Vtw dead after attn: exactly N fp32

    cast_x_kernel<<<(int)(N / 2048), 256, 0, stream>>>(X, Xb);
    pack_w_kernel<<<dim3(12, 12, 4), 256, 0, stream>>>(Wq, Wk, Wv, Wo, Wt);
    qkv_mfma_kernel<<<dim3(18, MTOT / 128), 256, 0, stream>>>(
        Xb, Wt, bq, bk, bv, Qw, Kw, Vtw);
    attn_kernel<<<dim3(SEQ / 256, BB * NHEADS, KS), 256, 0, stream>>>(
        Qw, Kw, Vtw, mask, Op, lpt);
    combine_kernel<<<(int)(N / 2048), 256, 0, stream>>>(Op, lpt, Ctxb, KS);
    out_mfma_kernel<<<dim3(6, MTOT / 128), 256, 0, stream>>>(
        Ctxb, Wt + (size_t)2304 * HID, bo, X, Rd);
    ln_kernel<<<MTOT, 256, 0, stream>>>(Rd, gamma, beta, out);
}

// Round 2
// 389.605 us; speedup vs baseline: 1.0207x; 1.0207x over previous
//
#include <hip/hip_runtime.h>
#include <hip/hip_bf16.h>

#define HID 768
#define NHEADS 12
#define HDIM 64
#define SEQ 4096
#define BB 2
#define MTOT (BB * SEQ)   // 8192 rows

typedef __attribute__((ext_vector_type(8))) short bf16x8;
typedef __attribute__((ext_vector_type(16))) float f32x16;

#define LOG2E 1.4426950408889634f

__device__ inline unsigned pack2bf(float a, float b) {
    __hip_bfloat162 h = __float22bfloat162_rn(float2{a, b});
    return *(unsigned*)&h;
}

// ---------------------------------------------------------------------------
// Kernel 0a: cast X fp32 -> bf16. grid 3072, block 256, 8 elems/thread.
// ---------------------------------------------------------------------------
__global__ __launch_bounds__(256) void cast_x_kernel(
    const float* __restrict__ X, __hip_bfloat16* __restrict__ Xb)
{
    const size_t i = ((size_t)blockIdx.x * 256 + threadIdx.x) * 8;
    const float4 x0 = *(const float4*)(X + i);
    const float4 x1 = *(const float4*)(X + i + 4);
    unsigned u[4];
    u[0] = pack2bf(x0.x, x0.y);
    u[1] = pack2bf(x0.z, x0.w);
    u[2] = pack2bf(x1.x, x1.y);
    u[3] = pack2bf(x1.z, x1.w);
    *(uint4*)(Xb + i) = *(uint4*)u;
}

// ---------------------------------------------------------------------------
// Kernel 0b: pack weights: W[in][out] fp32 -> Wt[out(global)][in] bf16.
// z=0..3 selects Wq,Wk,Wv,Wo; Wo at row offset 2304.
// ---------------------------------------------------------------------------
__global__ __launch_bounds__(256) void pack_w_kernel(
    const float* __restrict__ Wq, const float* __restrict__ Wk,
    const float* __restrict__ Wv, const float* __restrict__ Wo,
    __hip_bfloat16* __restrict__ Wt)
{
    const int z = blockIdx.z;
    const float* __restrict__ W = (z == 0) ? Wq : (z == 1) ? Wk : (z == 2) ? Wv : Wo;
    const int in0  = blockIdx.x * 64;
    const int out0 = blockIdx.y * 64;
    const int t = threadIdx.x;

    __shared__ float T[64][65];
#pragma unroll
    for (int i = 0; i < 4; ++i) {
        const int idx = t + 256 * i;
        const int row = idx >> 4;
        const int c4  = (idx & 15) << 2;
        const float4 v = *(const float4*)(W + (size_t)(in0 + row) * HID + out0 + c4);
        T[row][c4 + 0] = v.x; T[row][c4 + 1] = v.y;
        T[row][c4 + 2] = v.z; T[row][c4 + 3] = v.w;
    }
    __syncthreads();

    const int o  = t >> 2;
    const int cb = (t & 3) << 4;
    __hip_bfloat16 tmp[16];
#pragma unroll
    for (int k = 0; k < 16; ++k)
        tmp[k] = __float2bfloat16(T[cb + k][o]);
    __hip_bfloat16* __restrict__ dst =
        Wt + (size_t)(z * HID + out0 + o) * HID + in0 + cb;
    *(uint4*)(dst)     = *(uint4*)(&tmp[0]);
    *(uint4*)(dst + 8) = *(uint4*)(&tmp[8]);
}

// ---------------------------------------------------------------------------
// Kernel 1: fused QKV MFMA GEMM. Q,K -> bf16 [b,h,s,64]; V -> bf16 [b,h,64,s]
// (transposed in-epilogue via LDS). grid (18, 64), block 256, 128x128, BK=64.
// ---------------------------------------------------------------------------
__global__ __launch_bounds__(256) void qkv_mfma_kernel(
    const __hip_bfloat16* __restrict__ Xb, const __hip_bfloat16* __restrict__ Wt,
    const float* __restrict__ bq, const float* __restrict__ bk,
    const float* __restrict__ bv,
    __hip_bfloat16* __restrict__ Qo, __hip_bfloat16* __restrict__ Ko,
    __hip_bfloat16* __restrict__ Vo)
{
    const int nblk = blockIdx.x;          // 0..17
    const int z  = nblk / 6;              // 0=Q,1=K,2=V
    const int f0 = (nblk % 6) * 128;      // feature base within segment
    const int n0 = nblk * 128;            // row base in Wt
    const int m0 = blockIdx.y * 128;

    const float* __restrict__ bias = (z == 0) ? bq : (z == 1) ? bk : bv;

    const int t    = threadIdx.x;
    const int w    = t >> 6;
    const int lane = t & 63;
    const int col  = lane & 31;
    const int g    = lane >> 5;
    const int wm   = w & 1;
    const int wn   = w >> 1;

    __shared__ __hip_bfloat16 smem[2 * 128 * 72];   // As | Bs; Ts overlays both
    __hip_bfloat16 (*As)[72] = (__hip_bfloat16(*)[72])smem;
    __hip_bfloat16 (*Bs)[72] = (__hip_bfloat16(*)[72])(smem + 128 * 72);

    f32x16 acc[2][2];
#pragma unroll
    for (int mt = 0; mt < 2; ++mt)
#pragma unroll
        for (int nt = 0; nt < 2; ++nt)
#pragma unroll
            for (int r = 0; r < 16; ++r) acc[mt][nt][r] = 0.f;

    for (int k0 = 0; k0 < HID; k0 += 64) {
        __syncthreads();
#pragma unroll
        for (int i = 0; i < 4; ++i) {
            const int idx = t + 256 * i;     // 0..1023
            const int row = idx >> 3;        // 0..127
            const int c8  = (idx & 7) << 3;  // 0..56
            *(uint4*)&As[row][c8] = *(const uint4*)(Xb + (size_t)(m0 + row) * HID + k0 + c8);
            *(uint4*)&Bs[row][c8] = *(const uint4*)(Wt + (size_t)(n0 + row) * HID + k0 + c8);
        }
        __syncthreads();
#pragma unroll
        for (int kh = 0; kh < 4; ++kh) {
            const int ko = 16 * kh + 8 * g;
            const bf16x8 a0 = *(const bf16x8*)&As[64 * wm + col][ko];
            const bf16x8 a1 = *(const bf16x8*)&As[64 * wm + 32 + col][ko];
            const bf16x8 b0 = *(const bf16x8*)&Bs[64 * wn + col][ko];
            const bf16x8 b1 = *(const bf16x8*)&Bs[64 * wn + 32 + col][ko];
            acc[0][0] = __builtin_amdgcn_mfma_f32_32x32x16_bf16(a0, b0, acc[0][0], 0, 0, 0);
            acc[0][1] = __builtin_amdgcn_mfma_f32_32x32x16_bf16(a0, b1, acc[0][1], 0, 0, 0);
            acc[1][0] = __builtin_amdgcn_mfma_f32_32x32x16_bf16(a1, b0, acc[1][0], 0, 0, 0);
            acc[1][1] = __builtin_amdgcn_mfma_f32_32x32x16_bf16(a1, b1, acc[1][1], 0, 0, 0);
        }
    }

    if (z < 2) {
        __hip_bfloat16* __restrict__ Out = (z == 0) ? Qo : Ko;
        const int h = (f0 >> 6) + wn;
#pragma unroll
        for (int mt = 0; mt < 2; ++mt)
#pragma unroll
            for (int nt = 0; nt < 2; ++nt) {
                const int d = 32 * nt + col;
                const float bsv = bias[f0 + 64 * wn + d];
#pragma unroll
                for (int r = 0; r < 16; ++r) {
                    const int m = m0 + 64 * wm + 32 * mt + (r & 3) + 8 * (r >> 2) + 4 * g;
                    const int b = m >> 12;
                    const int s = m & (SEQ - 1);
                    Out[(((size_t)(b * NHEADS + h)) * SEQ + s) * HDIM + d] =
                        __float2bfloat16(acc[mt][nt][r] + bsv);
                }
            }
    } else {
        // V: transpose 128x128 tile via LDS, write Vt [bh][d][s]
        __syncthreads();   // K-loop LDS reads done before overlay
        __hip_bfloat16 (*Ts)[136] = (__hip_bfloat16(*)[136])smem;  // 34816 B
#pragma unroll
        for (int mt = 0; mt < 2; ++mt)
#pragma unroll
            for (int nt = 0; nt < 2; ++nt) {
                const int nloc = 64 * wn + 32 * nt + col;
                const float bsv = bias[f0 + nloc];
#pragma unroll
                for (int rg = 0; rg < 4; ++rg) {
                    const int mbase = 64 * wm + 32 * mt + 8 * rg + 4 * g;
                    unsigned pu[2];
                    pu[0] = pack2bf(acc[mt][nt][4 * rg + 0] + bsv,
                                    acc[mt][nt][4 * rg + 1] + bsv);
                    pu[1] = pack2bf(acc[mt][nt][4 * rg + 2] + bsv,
                                    acc[mt][nt][4 * rg + 3] + bsv);
                    *(uint2*)&Ts[nloc][mbase] = *(uint2*)pu;
                }
            }
        __syncthreads();
        const int nloc = t >> 1;
        const int half = t & 1;
        const int hh = (f0 >> 6) + (nloc >> 6);
        const int d  = nloc & 63;
        const int bb = m0 >> 12;
        const int s0 = m0 & (SEQ - 1);
        __hip_bfloat16* __restrict__ dst =
            Vo + (((size_t)(bb * NHEADS + hh)) * HDIM + d) * SEQ + s0 + 64 * half;
        const __hip_bfloat16* srcp = &Ts[nloc][64 * half];
#pragma unroll
        for (int j = 0; j < 8; ++j)
            *(uint4*)(dst + 8 * j) = *(const uint4*)(srcp + 8 * j);
    }
}

// ---------------------------------------------------------------------------
// Kernel 2: MFMA flash attention (S^T-swap, K-split). exp2-folded softmax.
// launch_bounds(256,2): unified VGPR+acc footprint must stay <256 regs.
// ROUND-2 LESSON (round 1 post-mortem): hoisting the packed-P arrays across
// both mt (loop interchange) spilled to scratch — WRITE_SIZE 50.7->108.5 MB,
// attn 158->218us. Keep the per-mt softmax->PV structure (peak liveness
// St64+O64+bq32+g4x16+stage16+addr ~= 212 < 256). Round-2 changes vs the
// 158us round-0 baseline, each structurally local:
//  - T14 async-STAGE: next K/V tile global loads issued into regs right
//    after the tile-ready barrier; ds_write at top of next iteration
//    (HBM latency hides under QK/softmax/PV compute). +16 VGPR.
//  - whole-kspan madd precomputed once into LDS (no per-tile mask staging
//    inside the barrier-coupled region). LDS only, no regs.
//  - P-transform via v_permlane32_swap_b32 (T12 primitive, m255: 1.20x vs
//    ds_bpermute) replacing 2 shfl_xor + divergent selects; drop-in within
//    the unchanged per-mt PV loop. Correctness of the mapping verified in
//    round 1 (absmax unchanged).
// Go/no-go signal next profile: attn WRITE_SIZE must be ~50.7 MB (no spill).
// ---------------------------------------------------------------------------
typedef __attribute__((ext_vector_type(2))) unsigned uswap2;

__global__ __launch_bounds__(256, 2) void attn_kernel(
    const __hip_bfloat16* __restrict__ Qb, const __hip_bfloat16* __restrict__ Kb,
    const __hip_bfloat16* __restrict__ Vt, const float* __restrict__ mask,
    __hip_bfloat16* __restrict__ Op, float* __restrict__ lp)
{
    const int bh = blockIdx.y;
    const int b  = bh / NHEADS;
    const int h  = bh - b * NHEADS;
    const int kspan = SEQ / gridDim.z;
    const int kbeg  = blockIdx.z * kspan;

    const int t    = threadIdx.x;
    const int w    = t >> 6;
    const int lane = t & 63;
    const int col  = lane & 31;
    const int g    = lane >> 5;
    const int qw   = blockIdx.x * 256 + 64 * w;

    __shared__ __hip_bfloat16 Ks[64][72];
    __shared__ __hip_bfloat16 Vts[64][72];
    __shared__ float madd[2048];   // whole kspan (max SEQ/2), premult by log2(e)

    const __hip_bfloat16* __restrict__ Qh = Qb + (size_t)bh * SEQ * HDIM;
    const __hip_bfloat16* __restrict__ Kh = Kb + (size_t)bh * SEQ * HDIM;
    const __hip_bfloat16* __restrict__ Vh = Vt + (size_t)bh * HDIM * SEQ;

    // whole-span additive mask, computed once (visible after iter-0 barriers)
    for (int j = t; j < kspan; j += 256)
        madd[j] = (1.0f - mask[b * SEQ + kbeg + j]) * (-10000.0f * LOG2E);

    bf16x8 bq[2][4];
#pragma unroll
    for (int mt = 0; mt < 2; ++mt)
#pragma unroll
        for (int kh = 0; kh < 4; ++kh)
            bq[mt][kh] = *(const bf16x8*)(Qh + (size_t)(qw + 32 * mt + col) * HDIM
                                          + 16 * kh + 8 * g);

    f32x16 O[2][2];
    float lac[2] = {0.f, 0.f};
#pragma unroll
    for (int mt = 0; mt < 2; ++mt)
#pragma unroll
        for (int dt = 0; dt < 2; ++dt)
#pragma unroll
            for (int r = 0; r < 16; ++r) O[mt][dt][r] = 0.f;

    const float kscale = 0.125f * LOG2E;

    // --- T14 staging pipeline: global -> regs (early) -> LDS (late) ---
    const int srow = t >> 3;          // 0..31
    const int sc8  = (t & 7) << 3;    // 0..56
    uint4 kreg[2], vreg[2];

#define ATTN_LOAD(KT)                                                          \
    kreg[0] = *(const uint4*)(Kh + (size_t)((KT) + srow) * HDIM + sc8);        \
    kreg[1] = *(const uint4*)(Kh + (size_t)((KT) + srow + 32) * HDIM + sc8);   \
    vreg[0] = *(const uint4*)(Vh + (size_t)srow * SEQ + (KT) + sc8);           \
    vreg[1] = *(const uint4*)(Vh + (size_t)(srow + 32) * SEQ + (KT) + sc8);

    ATTN_LOAD(kbeg);

    for (int kt0 = 0; kt0 < kspan; kt0 += 64) {
        __syncthreads();               // prev tile's LDS reads done (all waves)
        *(uint4*)&Ks[srow][sc8]       = kreg[0];
        *(uint4*)&Ks[srow + 32][sc8]  = kreg[1];
        *(uint4*)&Vts[srow][sc8]      = vreg[0];
        *(uint4*)&Vts[srow + 32][sc8] = vreg[1];
        __syncthreads();               // tile ready
        if (kt0 + 64 < kspan) { ATTN_LOAD(kbeg + kt0 + 64); }  // in flight during compute

        // ---- QK^T (swapped: St[k][q]) ----
        f32x16 St[2][2];
#pragma unroll
        for (int mt = 0; mt < 2; ++mt)
#pragma unroll
            for (int nt = 0; nt < 2; ++nt)
#pragma unroll
                for (int r = 0; r < 16; ++r) St[mt][nt][r] = 0.f;

#pragma unroll
        for (int kh = 0; kh < 4; ++kh) {
            const bf16x8 ak0 = *(const bf16x8*)&Ks[col][16 * kh + 8 * g];
            const bf16x8 ak1 = *(const bf16x8*)&Ks[32 + col][16 * kh + 8 * g];
            St[0][0] = __builtin_amdgcn_mfma_f32_32x32x16_bf16(ak0, bq[0][kh], St[0][0], 0, 0, 0);
            St[1][0] = __builtin_amdgcn_mfma_f32_32x32x16_bf16(ak0, bq[1][kh], St[1][0], 0, 0, 0);
            St[0][1] = __builtin_amdgcn_mfma_f32_32x32x16_bf16(ak1, bq[0][kh], St[0][1], 0, 0, 0);
            St[1][1] = __builtin_amdgcn_mfma_f32_32x32x16_bf16(ak1, bq[1][kh], St[1][1], 0, 0, 0);
        }

        // ---- per-mt softmax exp+pack, then PV (round-0 structure) ----
#pragma unroll
        for (int mt = 0; mt < 2; ++mt) {
            unsigned g4x[2][4], g4y[2][4];
#pragma unroll
            for (int nt = 0; nt < 2; ++nt) {
#pragma unroll
                for (int b4 = 0; b4 < 4; ++b4) {
                    const float4 mm = *(const float4*)&madd[kt0 + 32 * nt + 8 * b4 + 4 * g];
                    const float p0 = __builtin_amdgcn_exp2f(fmaf(St[mt][nt][4 * b4 + 0], kscale, mm.x));
                    const float p1 = __builtin_amdgcn_exp2f(fmaf(St[mt][nt][4 * b4 + 1], kscale, mm.y));
                    const float p2 = __builtin_amdgcn_exp2f(fmaf(St[mt][nt][4 * b4 + 2], kscale, mm.z));
                    const float p3 = __builtin_amdgcn_exp2f(fmaf(St[mt][nt][4 * b4 + 3], kscale, mm.w));
                    lac[mt] += (p0 + p1) + (p2 + p3);
                    g4x[nt][b4] = pack2bf(p0, p1);
                    g4y[nt][b4] = pack2bf(p2, p3);
                }
            }
#pragma unroll
            for (int kh = 0; kh < 4; ++kh) {
                const int nt  = kh >> 1;
                const int khl = kh & 1;
                union { unsigned u[4]; bf16x8 v; } au;
#if __has_builtin(__builtin_amdgcn_permlane32_swap)
                // swap(vdst=lo, src=hi): vdst[32..63] <-> src[0..31].
                // result[0] = l<32 ? lo[l] : hi[l-32]; result[1] = l<32 ? lo[l+32] : hi[l]
                // == exactly A-frag words u0/u2 (verified round 1, absmax unchanged).
                uswap2 sx = __builtin_amdgcn_permlane32_swap(
                    g4x[nt][2 * khl], g4x[nt][2 * khl + 1], false, false);
                uswap2 sy = __builtin_amdgcn_permlane32_swap(
                    g4y[nt][2 * khl], g4y[nt][2 * khl + 1], false, false);
                au.u[0] = sx[0]; au.u[1] = sy[0]; au.u[2] = sx[1]; au.u[3] = sy[1];
#else
                const unsigned lo_x = g4x[nt][2 * khl],     lo_y = g4y[nt][2 * khl];
                const unsigned hi_x = g4x[nt][2 * khl + 1], hi_y = g4y[nt][2 * khl + 1];
                const unsigned sxv = g ? lo_x : hi_x;
                const unsigned syv = g ? lo_y : hi_y;
                const unsigned rx = (unsigned)__shfl_xor((int)sxv, 32, 64);
                const unsigned ry = (unsigned)__shfl_xor((int)syv, 32, 64);
                if (g) { au.u[0] = rx; au.u[1] = ry; au.u[2] = hi_x; au.u[3] = hi_y; }
                else   { au.u[0] = lo_x; au.u[1] = lo_y; au.u[2] = rx; au.u[3] = ry; }
#endif
                const bf16x8 bv0 = *(const bf16x8*)&Vts[col][16 * kh + 8 * g];
                const bf16x8 bv1 = *(const bf16x8*)&Vts[32 + col][16 * kh + 8 * g];
                O[mt][0] = __builtin_amdgcn_mfma_f32_32x32x16_bf16(au.v, bv0, O[mt][0], 0, 0, 0);
                O[mt][1] = __builtin_amdgcn_mfma_f32_32x32x16_bf16(au.v, bv1, O[mt][1], 0, 0, 0);
            }
        }
    }
#undef ATTN_LOAD

    const size_t opbase = (size_t)blockIdx.z * ((size_t)MTOT * HID);
#pragma unroll
    for (int mt = 0; mt < 2; ++mt) {
        const float l = lac[mt] + __shfl_xor(lac[mt], 32, 64);
        if (g == 0)
            lp[((size_t)blockIdx.z * (BB * NHEADS) + bh) * SEQ + qw + 32 * mt + col] = l;
#pragma unroll
        for (int dt = 0; dt < 2; ++dt)
#pragma unroll
            for (int r = 0; r < 16; ++r) {
                const int q = qw + 32 * mt + (r & 3) + 8 * (r >> 2) + 4 * g;
                const int d = 32 * dt + col;
                Op[opbase + ((size_t)b * SEQ + q) * HID + h * HDIM + d] =
                    __float2bfloat16(O[mt][dt][r]);
            }
    }
}

// ---------------------------------------------------------------------------
// Kernel 2b: combine K-split partials -> Ctx bf16. 8 elems/thread.
// ---------------------------------------------------------------------------
__global__ __launch_bounds__(256) void combine_kernel(
    const __hip_bfloat16* __restrict__ Op, const float* __restrict__ lp,
    __hip_bfloat16* __restrict__ Ctx, int KS)
{
    const size_t i = ((size_t)blockIdx.x * 256 + threadIdx.x) * 8;
    const int n   = (int)(i % HID);
    const int row = (int)(i / HID);
    const int h = n >> 6;
    const int b = row >> 12;
    const int q = row & (SEQ - 1);
    const int bh = b * NHEADS + h;

    float denom = 0.f;
    float o[8] = {};
    for (int kz = 0; kz < KS; ++kz) {
        denom += lp[((size_t)kz * (BB * NHEADS) + bh) * SEQ + q];
        uint4 u = *(const uint4*)(Op + (size_t)kz * ((size_t)MTOT * HID) + i);
        const __hip_bfloat16* e = (const __hip_bfloat16*)&u;
#pragma unroll
        for (int j = 0; j < 8; ++j) o[j] += __bfloat162float(e[j]);
    }
    const float inv = 1.0f / denom;
    unsigned u[4];
#pragma unroll
    for (int j = 0; j < 4; ++j)
        u[j] = pack2bf(o[2 * j] * inv, o[2 * j + 1] * inv);
    *(uint4*)(Ctx + i) = *(uint4*)u;
}

// ---------------------------------------------------------------------------
// Kernel 3: output projection MFMA + bias + residual -> Resid fp32.
// grid (6, 64), block 256.
// ---------------------------------------------------------------------------
__global__ __launch_bounds__(256) void out_mfma_kernel(
    const __hip_bfloat16* __restrict__ Cb, const __hip_bfloat16* __restrict__ Wto,
    const float* __restrict__ bo, const float* __restrict__ X,
    float* __restrict__ Resid)
{
    const int n0 = blockIdx.x * 128;
    const int m0 = blockIdx.y * 128;

    const int t    = threadIdx.x;
    const int w    = t >> 6;
    const int lane = t & 63;
    const int col  = lane & 31;
    const int g    = lane >> 5;
    const int wm   = w & 1;
    const int wn   = w >> 1;

    __shared__ __hip_bfloat16 As[128][72];
    __shared__ __hip_bfloat16 Bs[128][72];

    f32x16 acc[2][2];
#pragma unroll
    for (int mt = 0; mt < 2; ++mt)
#pragma unroll
        for (int nt = 0; nt < 2; ++nt)
#pragma unroll
            for (int r = 0; r < 16; ++r) acc[mt][nt][r] = 0.f;

    for (int k0 = 0; k0 < HID; k0 += 64) {
        __syncthreads();
#pragma unroll
        for (int i = 0; i < 4; ++i) {
            const int idx = t + 256 * i;
            const int row = idx >> 3;
            const int c8  = (idx & 7) << 3;
            *(uint4*)&As[row][c8] = *(const uint4*)(Cb  + (size_t)(m0 + row) * HID + k0 + c8);
            *(uint4*)&Bs[row][c8] = *(const uint4*)(Wto + (size_t)(n0 + row) * HID + k0 + c8);
        }
        __syncthreads();
#pragma unroll
        for (int kh = 0; kh < 4; ++kh) {
            const int ko = 16 * kh + 8 * g;
            const bf16x8 a0 = *(const bf16x8*)&As[64 * wm + col][ko];
            const bf16x8 a1 = *(const bf16x8*)&As[64 * wm + 32 + col][ko];
            const bf16x8 b0 = *(const bf16x8*)&Bs[64 * wn + col][ko];
            const bf16x8 b1 = *(const bf16x8*)&Bs[64 * wn + 32 + col][ko];
            acc[0][0] = __builtin_amdgcn_mfma_f32_32x32x16_bf16(a0, b0, acc[0][0], 0, 0, 0);
            acc[0][1] = __builtin_amdgcn_mfma_f32_32x32x16_bf16(a0, b1, acc[0][1], 0, 0, 0);
            acc[1][0] = __builtin_amdgcn_mfma_f32_32x32x16_bf16(a1, b0, acc[1][0], 0, 0, 0);
            acc[1][1] = __builtin_amdgcn_mfma_f32_32x32x16_bf16(a1, b1, acc[1][1], 0, 0, 0);
        }
    }

#pragma unroll
    for (int mt = 0; mt < 2; ++mt)
#pragma unroll
        for (int nt = 0; nt < 2; ++nt) {
            const int n = n0 + 64 * wn + 32 * nt + col;
            const float bsv = bo[n];
#pragma unroll
            for (int r = 0; r < 16; ++r) {
                const int m = m0 + 64 * wm + 32 * mt + (r & 3) + 8 * (r >> 2) + 4 * g;
                Resid[(size_t)m * HID + n] = acc[mt][nt][r] + bsv + X[(size_t)m * HID + n];
            }
        }
}

// ---------------------------------------------------------------------------
// Kernel 4: LayerNorm.
// ---------------------------------------------------------------------------
__global__ __launch_bounds__(256) void ln_kernel(
    const float* __restrict__ Rin, const float* __restrict__ gamma,
    const float* __restrict__ beta, float* __restrict__ Out)
{
    const int row = blockIdx.x;
    const int t   = threadIdx.x;
    const float* __restrict__ x = Rin + (size_t)row * HID;

    const float v0 = x[t];
    const float v1 = x[t + 256];
    const float v2 = x[t + 512];
    float s  = v0 + v1 + v2;
    float s2 = v0 * v0 + v1 * v1 + v2 * v2;
#pragma unroll
    for (int off = 32; off; off >>= 1) {
        s  += __shfl_xor(s,  off, 64);
        s2 += __shfl_xor(s2, off, 64);
    }
    __shared__ float rs[4], rs2[4];
    const int w = t >> 6, lane = t & 63;
    if (lane == 0) { rs[w] = s; rs2[w] = s2; }
    __syncthreads();
    const float tot  = rs[0] + rs[1] + rs[2] + rs[3];
    const float tot2 = rs2[0] + rs2[1] + rs2[2] + rs2[3];
    const float mu   = tot * (1.0f / HID);
    const float var  = tot2 * (1.0f / HID) - mu * mu;
    const float rsig = rsqrtf(var + 1e-5f);

    float* __restrict__ y = Out + (size_t)row * HID;
    y[t]       = (v0 - mu) * rsig * gamma[t]       + beta[t];
    y[t + 256] = (v1 - mu) * rsig * gamma[t + 256] + beta[t + 256];
    y[t + 512] = (v2 - mu) * rsig * gamma[t + 512] + beta[t + 512];
}

// ---------------------------------------------------------------------------
extern "C" void kernel_launch(void* const* d_in, const int* in_sizes, int n_in,
                              void* d_out, int out_size, void* d_ws, size_t ws_size,
                              hipStream_t stream)
{
    const float* X     = (const float*)d_in[0];
    const float* mask  = (const float*)d_in[1];
    const float* Wq    = (const float*)d_in[2];
    const float* bq    = (const float*)d_in[3];
    const float* Wk    = (const float*)d_in[4];
    const float* bk    = (const float*)d_in[5];
    const float* Wv    = (const float*)d_in[6];
    const float* bv    = (const float*)d_in[7];
    const float* Wo    = (const float*)d_in[8];
    const float* bo    = (const float*)d_in[9];
    const float* gamma = (const float*)d_in[10];
    const float* beta  = (const float*)d_in[11];
    float* out = (float*)d_out;

    const size_t N = (size_t)MTOT * HID;        // 6,291,456 elements
    const size_t WTE = (size_t)4 * HID * HID;

    char* p = (char*)d_ws;
    __hip_bfloat16* Xb  = (__hip_bfloat16*)p;  p += 2 * N;
    __hip_bfloat16* Wt  = (__hip_bfloat16*)p;  p += 2 * WTE;
    __hip_bfloat16* Qw  = (__hip_bfloat16*)p;  p += 2 * N;
    __hip_bfloat16* Kw  = (__hip_bfloat16*)p;  p += 2 * N;
    __hip_bfloat16* Vtw = (__hip_bfloat16*)p;  p += 2 * N;
    char* opb = p;
    const size_t fixed = (size_t)(opb - (char*)d_ws);

    const size_t lpsz4 = 4 * (size_t)(BB * NHEADS) * SEQ * sizeof(float);
    const int KS = (ws_size >= fixed + 4 * 2 * N + lpsz4) ? 4 : 2;

    __hip_bfloat16* Op  = (__hip_bfloat16*)opb;          // KS*N bf16 partial O
    float* lpt = (float*)(opb + (size_t)KS * 2 * N);     // KS*24*SEQ fp32
    __hip_bfloat16* Ctxb = Xb;      // Xb dead after qkv
    float* Rd = (float*)Kw;         // Kw+Vtw dead after attn: exactly N fp32

    cast_x_kernel<<<(int)(N / 2048), 256, 0, stream>>>(X, Xb);
    pack_w_kernel<<<dim3(12, 12, 4), 256, 0, stream>>>(Wq, Wk, Wv, Wo, Wt);
    qkv_mfma_kernel<<<dim3(18, MTOT / 128), 256, 0, stream>>>(
        Xb, Wt, bq, bk, bv, Qw, Kw, Vtw);
    attn_kernel<<<dim3(SEQ / 256, BB * NHEADS, KS), 256, 0, stream>>>(
        Qw, Kw, Vtw, mask, Op, lpt);
    combine_kernel<<<(int)(N / 2048), 256, 0, stream>>>(Op, lpt, Ctxb, KS);
    out_mfma_kernel<<<dim3(6, MTOT / 128), 256, 0, stream>>>(
        Ctxb, Wt + (size_t)2304 * HID, bo, X, Rd);
    ln_kernel<<<MTOT, 256, 0, stream>>>(Rd, gamma, beta, out);
}

// Round 3
// 341.152 us; speedup vs baseline: 1.1657x; 1.1420x over previous
//
#include <hip/hip_runtime.h>
#include <hip/hip_bf16.h>

#define HID 768
#define NHEADS 12
#define HDIM 64
#define SEQ 4096
#define BB 2
#define MTOT (BB * SEQ)   // 8192 rows

typedef __attribute__((ext_vector_type(8))) short bf16x8;
typedef __attribute__((ext_vector_type(16))) float f32x16;

#define LOG2E 1.4426950408889634f

__device__ inline unsigned pack2bf(float a, float b) {
    __hip_bfloat162 h = __float22bfloat162_rn(float2{a, b});
    return *(unsigned*)&h;
}

// ---------------------------------------------------------------------------
// Kernel 0a: cast X fp32 -> bf16. grid 3072, block 256, 8 elems/thread.
// ---------------------------------------------------------------------------
__global__ __launch_bounds__(256) void cast_x_kernel(
    const float* __restrict__ X, __hip_bfloat16* __restrict__ Xb)
{
    const size_t i = ((size_t)blockIdx.x * 256 + threadIdx.x) * 8;
    const float4 x0 = *(const float4*)(X + i);
    const float4 x1 = *(const float4*)(X + i + 4);
    unsigned u[4];
    u[0] = pack2bf(x0.x, x0.y);
    u[1] = pack2bf(x0.z, x0.w);
    u[2] = pack2bf(x1.x, x1.y);
    u[3] = pack2bf(x1.z, x1.w);
    *(uint4*)(Xb + i) = *(uint4*)u;
}

// ---------------------------------------------------------------------------
// Kernel 0b: pack weights: W[in][out] fp32 -> Wt[out(global)][in] bf16.
// z=0..3 selects Wq,Wk,Wv,Wo; Wo at row offset 2304.
// ---------------------------------------------------------------------------
__global__ __launch_bounds__(256) void pack_w_kernel(
    const float* __restrict__ Wq, const float* __restrict__ Wk,
    const float* __restrict__ Wv, const float* __restrict__ Wo,
    __hip_bfloat16* __restrict__ Wt)
{
    const int z = blockIdx.z;
    const float* __restrict__ W = (z == 0) ? Wq : (z == 1) ? Wk : (z == 2) ? Wv : Wo;
    const int in0  = blockIdx.x * 64;
    const int out0 = blockIdx.y * 64;
    const int t = threadIdx.x;

    __shared__ float T[64][65];
#pragma unroll
    for (int i = 0; i < 4; ++i) {
        const int idx = t + 256 * i;
        const int row = idx >> 4;
        const int c4  = (idx & 15) << 2;
        const float4 v = *(const float4*)(W + (size_t)(in0 + row) * HID + out0 + c4);
        T[row][c4 + 0] = v.x; T[row][c4 + 1] = v.y;
        T[row][c4 + 2] = v.z; T[row][c4 + 3] = v.w;
    }
    __syncthreads();

    const int o  = t >> 2;
    const int cb = (t & 3) << 4;
    __hip_bfloat16 tmp[16];
#pragma unroll
    for (int k = 0; k < 16; ++k)
        tmp[k] = __float2bfloat16(T[cb + k][o]);
    __hip_bfloat16* __restrict__ dst =
        Wt + (size_t)(z * HID + out0 + o) * HID + in0 + cb;
    *(uint4*)(dst)     = *(uint4*)(&tmp[0]);
    *(uint4*)(dst + 8) = *(uint4*)(&tmp[8]);
}

// ---------------------------------------------------------------------------
// Kernel 1: fused QKV MFMA GEMM. Q,K -> bf16 [b,h,s,64]; V -> bf16 [b,h,64,s]
// (transposed in-epilogue via LDS). grid (18, 64), block 256, 128x128, BK=64.
// ---------------------------------------------------------------------------
__global__ __launch_bounds__(256) void qkv_mfma_kernel(
    const __hip_bfloat16* __restrict__ Xb, const __hip_bfloat16* __restrict__ Wt,
    const float* __restrict__ bq, const float* __restrict__ bk,
    const float* __restrict__ bv,
    __hip_bfloat16* __restrict__ Qo, __hip_bfloat16* __restrict__ Ko,
    __hip_bfloat16* __restrict__ Vo)
{
    const int nblk = blockIdx.x;          // 0..17
    const int z  = nblk / 6;              // 0=Q,1=K,2=V
    const int f0 = (nblk % 6) * 128;      // feature base within segment
    const int n0 = nblk * 128;            // row base in Wt
    const int m0 = blockIdx.y * 128;

    const float* __restrict__ bias = (z == 0) ? bq : (z == 1) ? bk : bv;

    const int t    = threadIdx.x;
    const int w    = t >> 6;
    const int lane = t & 63;
    const int col  = lane & 31;
    const int g    = lane >> 5;
    const int wm   = w & 1;
    const int wn   = w >> 1;

    __shared__ __hip_bfloat16 smem[2 * 128 * 72];   // As | Bs; Ts overlays both
    __hip_bfloat16 (*As)[72] = (__hip_bfloat16(*)[72])smem;
    __hip_bfloat16 (*Bs)[72] = (__hip_bfloat16(*)[72])(smem + 128 * 72);

    f32x16 acc[2][2];
#pragma unroll
    for (int mt = 0; mt < 2; ++mt)
#pragma unroll
        for (int nt = 0; nt < 2; ++nt)
#pragma unroll
            for (int r = 0; r < 16; ++r) acc[mt][nt][r] = 0.f;

    for (int k0 = 0; k0 < HID; k0 += 64) {
        __syncthreads();
#pragma unroll
        for (int i = 0; i < 4; ++i) {
            const int idx = t + 256 * i;     // 0..1023
            const int row = idx >> 3;        // 0..127
            const int c8  = (idx & 7) << 3;  // 0..56
            *(uint4*)&As[row][c8] = *(const uint4*)(Xb + (size_t)(m0 + row) * HID + k0 + c8);
            *(uint4*)&Bs[row][c8] = *(const uint4*)(Wt + (size_t)(n0 + row) * HID + k0 + c8);
        }
        __syncthreads();
#pragma unroll
        for (int kh = 0; kh < 4; ++kh) {
            const int ko = 16 * kh + 8 * g;
            const bf16x8 a0 = *(const bf16x8*)&As[64 * wm + col][ko];
            const bf16x8 a1 = *(const bf16x8*)&As[64 * wm + 32 + col][ko];
            const bf16x8 b0 = *(const bf16x8*)&Bs[64 * wn + col][ko];
            const bf16x8 b1 = *(const bf16x8*)&Bs[64 * wn + 32 + col][ko];
            acc[0][0] = __builtin_amdgcn_mfma_f32_32x32x16_bf16(a0, b0, acc[0][0], 0, 0, 0);
            acc[0][1] = __builtin_amdgcn_mfma_f32_32x32x16_bf16(a0, b1, acc[0][1], 0, 0, 0);
            acc[1][0] = __builtin_amdgcn_mfma_f32_32x32x16_bf16(a1, b0, acc[1][0], 0, 0, 0);
            acc[1][1] = __builtin_amdgcn_mfma_f32_32x32x16_bf16(a1, b1, acc[1][1], 0, 0, 0);
        }
    }

    if (z < 2) {
        __hip_bfloat16* __restrict__ Out = (z == 0) ? Qo : Ko;
        const int h = (f0 >> 6) + wn;
#pragma unroll
        for (int mt = 0; mt < 2; ++mt)
#pragma unroll
            for (int nt = 0; nt < 2; ++nt) {
                const int d = 32 * nt + col;
                const float bsv = bias[f0 + 64 * wn + d];
#pragma unroll
                for (int r = 0; r < 16; ++r) {
                    const int m = m0 + 64 * wm + 32 * mt + (r & 3) + 8 * (r >> 2) + 4 * g;
                    const int b = m >> 12;
                    const int s = m & (SEQ - 1);
                    Out[(((size_t)(b * NHEADS + h)) * SEQ + s) * HDIM + d] =
                        __float2bfloat16(acc[mt][nt][r] + bsv);
                }
            }
    } else {
        // V: transpose 128x128 tile via LDS, write Vt [bh][d][s]
        __syncthreads();   // K-loop LDS reads done before overlay
        __hip_bfloat16 (*Ts)[136] = (__hip_bfloat16(*)[136])smem;  // 34816 B
#pragma unroll
        for (int mt = 0; mt < 2; ++mt)
#pragma unroll
            for (int nt = 0; nt < 2; ++nt) {
                const int nloc = 64 * wn + 32 * nt + col;
                const float bsv = bias[f0 + nloc];
#pragma unroll
                for (int rg = 0; rg < 4; ++rg) {
                    const int mbase = 64 * wm + 32 * mt + 8 * rg + 4 * g;
                    unsigned pu[2];
                    pu[0] = pack2bf(acc[mt][nt][4 * rg + 0] + bsv,
                                    acc[mt][nt][4 * rg + 1] + bsv);
                    pu[1] = pack2bf(acc[mt][nt][4 * rg + 2] + bsv,
                                    acc[mt][nt][4 * rg + 3] + bsv);
                    *(uint2*)&Ts[nloc][mbase] = *(uint2*)pu;
                }
            }
        __syncthreads();
        const int nloc = t >> 1;
        const int half = t & 1;
        const int hh = (f0 >> 6) + (nloc >> 6);
        const int d  = nloc & 63;
        const int bb = m0 >> 12;
        const int s0 = m0 & (SEQ - 1);
        __hip_bfloat16* __restrict__ dst =
            Vo + (((size_t)(bb * NHEADS + hh)) * HDIM + d) * SEQ + s0 + 64 * half;
        const __hip_bfloat16* srcp = &Ts[nloc][64 * half];
#pragma unroll
        for (int j = 0; j < 8; ++j)
            *(uint4*)(dst + 8 * j) = *(const uint4*)(srcp + 8 * j);
    }
}

// ---------------------------------------------------------------------------
// Kernel 2: MFMA flash attention (S^T-swap, K-split). exp2-folded softmax.
// REGISTER BUDGET NOTE (rounds 1-2 post-mortem): at (256,2) the unified
// budget is 256 regs/wave and round-0's working set (~120 arch VGPR +
// 128 acc f32 for St+O) is ~248 — there is NO headroom. T14 reg-staging
// (+16 VGPR live across compute) overflowed it: ~8 regs spilled per tile,
// WRITE_SIZE 50.7->108 MB, attn 158->217us. Counters were identical with
// and without the round-1 loop interchange, acquitting it. Do not add
// live-across-compute registers to this kernel.
// Round-3 deltas vs round-0 (all zero-register):
//  - whole-kspan madd precomputed once into LDS (removes per-tile mask
//    global read + LDS write from the barrier-coupled region).
//  - P-transform via v_permlane32_swap_b32 (T12 primitive) replacing
//    2 shfl_xor + divergent selects (mapping verified: absmax unchanged).
//  - T5 s_setprio(1) tight around MFMA clusters (QK block, PV pairs):
//    4-wave blocks drift out of phase across the long barrier-free compute
//    section -> scheduler can prefer MFMA-issuing waves (m191 attn regime).
// Go/no-go on next profile: WRITE_SIZE ~50.7 MB, SGPR ~32 (spill gone).
// ---------------------------------------------------------------------------
typedef __attribute__((ext_vector_type(2))) unsigned uswap2;

__global__ __launch_bounds__(256, 2) void attn_kernel(
    const __hip_bfloat16* __restrict__ Qb, const __hip_bfloat16* __restrict__ Kb,
    const __hip_bfloat16* __restrict__ Vt, const float* __restrict__ mask,
    __hip_bfloat16* __restrict__ Op, float* __restrict__ lp)
{
    const int bh = blockIdx.y;
    const int b  = bh / NHEADS;
    const int h  = bh - b * NHEADS;
    const int kspan = SEQ / gridDim.z;
    const int kbeg  = blockIdx.z * kspan;

    const int t    = threadIdx.x;
    const int w    = t >> 6;
    const int lane = t & 63;
    const int col  = lane & 31;
    const int g    = lane >> 5;
    const int qw   = blockIdx.x * 256 + 64 * w;

    __shared__ __hip_bfloat16 Ks[64][72];
    __shared__ __hip_bfloat16 Vts[64][72];
    __shared__ float madd[2048];   // whole kspan (max SEQ/2), premult by log2(e)

    const __hip_bfloat16* __restrict__ Qh = Qb + (size_t)bh * SEQ * HDIM;
    const __hip_bfloat16* __restrict__ Kh = Kb + (size_t)bh * SEQ * HDIM;
    const __hip_bfloat16* __restrict__ Vh = Vt + (size_t)bh * HDIM * SEQ;

    // whole-span additive mask, computed once (visible after iter-0 barriers)
    for (int j = t; j < kspan; j += 256)
        madd[j] = (1.0f - mask[b * SEQ + kbeg + j]) * (-10000.0f * LOG2E);

    bf16x8 bq[2][4];
#pragma unroll
    for (int mt = 0; mt < 2; ++mt)
#pragma unroll
        for (int kh = 0; kh < 4; ++kh)
            bq[mt][kh] = *(const bf16x8*)(Qh + (size_t)(qw + 32 * mt + col) * HDIM
                                          + 16 * kh + 8 * g);

    f32x16 O[2][2];
    float lac[2] = {0.f, 0.f};
#pragma unroll
    for (int mt = 0; mt < 2; ++mt)
#pragma unroll
        for (int dt = 0; dt < 2; ++dt)
#pragma unroll
            for (int r = 0; r < 16; ++r) O[mt][dt][r] = 0.f;

    const float kscale = 0.125f * LOG2E;

    for (int kt0 = 0; kt0 < kspan; kt0 += 64) {
        const int kt = kbeg + kt0;
        __syncthreads();               // prev tile's LDS reads done (all waves)
#pragma unroll
        for (int i = 0; i < 2; ++i) {
            const int idx = t + 256 * i;
            const int row = idx >> 3;
            const int c8  = (idx & 7) << 3;
            *(uint4*)&Ks[row][c8]  = *(const uint4*)(Kh + (size_t)(kt + row) * HDIM + c8);
            *(uint4*)&Vts[row][c8] = *(const uint4*)(Vh + (size_t)row * SEQ + kt + c8);
        }
        __syncthreads();               // tile ready

        // ---- QK^T (swapped: St[k][q]) ----
        f32x16 St[2][2];
#pragma unroll
        for (int mt = 0; mt < 2; ++mt)
#pragma unroll
            for (int nt = 0; nt < 2; ++nt)
#pragma unroll
                for (int r = 0; r < 16; ++r) St[mt][nt][r] = 0.f;

        __builtin_amdgcn_s_setprio(1);
#pragma unroll
        for (int kh = 0; kh < 4; ++kh) {
            const bf16x8 ak0 = *(const bf16x8*)&Ks[col][16 * kh + 8 * g];
            const bf16x8 ak1 = *(const bf16x8*)&Ks[32 + col][16 * kh + 8 * g];
            St[0][0] = __builtin_amdgcn_mfma_f32_32x32x16_bf16(ak0, bq[0][kh], St[0][0], 0, 0, 0);
            St[1][0] = __builtin_amdgcn_mfma_f32_32x32x16_bf16(ak0, bq[1][kh], St[1][0], 0, 0, 0);
            St[0][1] = __builtin_amdgcn_mfma_f32_32x32x16_bf16(ak1, bq[0][kh], St[0][1], 0, 0, 0);
            St[1][1] = __builtin_amdgcn_mfma_f32_32x32x16_bf16(ak1, bq[1][kh], St[1][1], 0, 0, 0);
        }
        __builtin_amdgcn_s_setprio(0);

        // ---- per-mt softmax exp+pack, then PV ----
#pragma unroll
        for (int mt = 0; mt < 2; ++mt) {
            unsigned g4x[2][4], g4y[2][4];
#pragma unroll
            for (int nt = 0; nt < 2; ++nt) {
#pragma unroll
                for (int b4 = 0; b4 < 4; ++b4) {
                    const float4 mm = *(const float4*)&madd[kt0 + 32 * nt + 8 * b4 + 4 * g];
                    const float p0 = __builtin_amdgcn_exp2f(fmaf(St[mt][nt][4 * b4 + 0], kscale, mm.x));
                    const float p1 = __builtin_amdgcn_exp2f(fmaf(St[mt][nt][4 * b4 + 1], kscale, mm.y));
                    const float p2 = __builtin_amdgcn_exp2f(fmaf(St[mt][nt][4 * b4 + 2], kscale, mm.z));
                    const float p3 = __builtin_amdgcn_exp2f(fmaf(St[mt][nt][4 * b4 + 3], kscale, mm.w));
                    lac[mt] += (p0 + p1) + (p2 + p3);
                    g4x[nt][b4] = pack2bf(p0, p1);
                    g4y[nt][b4] = pack2bf(p2, p3);
                }
            }
#pragma unroll
            for (int kh = 0; kh < 4; ++kh) {
                const int nt  = kh >> 1;
                const int khl = kh & 1;
                union { unsigned u[4]; bf16x8 v; } au;
#if __has_builtin(__builtin_amdgcn_permlane32_swap)
                // result[0] = l<32 ? lo[l] : hi[l-32]; result[1] = l<32 ? lo[l+32] : hi[l]
                // == exactly A-frag words u0/u2 (verified rounds 1-2, absmax unchanged).
                uswap2 sx = __builtin_amdgcn_permlane32_swap(
                    g4x[nt][2 * khl], g4x[nt][2 * khl + 1], false, false);
                uswap2 sy = __builtin_amdgcn_permlane32_swap(
                    g4y[nt][2 * khl], g4y[nt][2 * khl + 1], false, false);
                au.u[0] = sx[0]; au.u[1] = sy[0]; au.u[2] = sx[1]; au.u[3] = sy[1];
#else
                const unsigned lo_x = g4x[nt][2 * khl],     lo_y = g4y[nt][2 * khl];
                const unsigned hi_x = g4x[nt][2 * khl + 1], hi_y = g4y[nt][2 * khl + 1];
                const unsigned sxv = g ? lo_x : hi_x;
                const unsigned syv = g ? lo_y : hi_y;
                const unsigned rx = (unsigned)__shfl_xor((int)sxv, 32, 64);
                const unsigned ry = (unsigned)__shfl_xor((int)syv, 32, 64);
                if (g) { au.u[0] = rx; au.u[1] = ry; au.u[2] = hi_x; au.u[3] = hi_y; }
                else   { au.u[0] = lo_x; au.u[1] = lo_y; au.u[2] = rx; au.u[3] = ry; }
#endif
                const bf16x8 bv0 = *(const bf16x8*)&Vts[col][16 * kh + 8 * g];
                const bf16x8 bv1 = *(const bf16x8*)&Vts[32 + col][16 * kh + 8 * g];
                __builtin_amdgcn_s_setprio(1);
                O[mt][0] = __builtin_amdgcn_mfma_f32_32x32x16_bf16(au.v, bv0, O[mt][0], 0, 0, 0);
                O[mt][1] = __builtin_amdgcn_mfma_f32_32x32x16_bf16(au.v, bv1, O[mt][1], 0, 0, 0);
                __builtin_amdgcn_s_setprio(0);
            }
        }
    }

    const size_t opbase = (size_t)blockIdx.z * ((size_t)MTOT * HID);
#pragma unroll
    for (int mt = 0; mt < 2; ++mt) {
        const float l = lac[mt] + __shfl_xor(lac[mt], 32, 64);
        if (g == 0)
            lp[((size_t)blockIdx.z * (BB * NHEADS) + bh) * SEQ + qw + 32 * mt + col] = l;
#pragma unroll
        for (int dt = 0; dt < 2; ++dt)
#pragma unroll
            for (int r = 0; r < 16; ++r) {
                const int q = qw + 32 * mt + (r & 3) + 8 * (r >> 2) + 4 * g;
                const int d = 32 * dt + col;
                Op[opbase + ((size_t)b * SEQ + q) * HID + h * HDIM + d] =
                    __float2bfloat16(O[mt][dt][r]);
            }
    }
}

// ---------------------------------------------------------------------------
// Kernel 2b: combine K-split partials -> Ctx bf16. 8 elems/thread.
// ---------------------------------------------------------------------------
__global__ __launch_bounds__(256) void combine_kernel(
    const __hip_bfloat16* __restrict__ Op, const float* __restrict__ lp,
    __hip_bfloat16* __restrict__ Ctx, int KS)
{
    const size_t i = ((size_t)blockIdx.x * 256 + threadIdx.x) * 8;
    const int n   = (int)(i % HID);
    const int row = (int)(i / HID);
    const int h = n >> 6;
    const int b = row >> 12;
    const int q = row & (SEQ - 1);
    const int bh = b * NHEADS + h;

    float denom = 0.f;
    float o[8] = {};
    for (int kz = 0; kz < KS; ++kz) {
        denom += lp[((size_t)kz * (BB * NHEADS) + bh) * SEQ + q];
        uint4 u = *(const uint4*)(Op + (size_t)kz * ((size_t)MTOT * HID) + i);
        const __hip_bfloat16* e = (const __hip_bfloat16*)&u;
#pragma unroll
        for (int j = 0; j < 8; ++j) o[j] += __bfloat162float(e[j]);
    }
    const float inv = 1.0f / denom;
    unsigned u[4];
#pragma unroll
    for (int j = 0; j < 4; ++j)
        u[j] = pack2bf(o[2 * j] * inv, o[2 * j + 1] * inv);
    *(uint4*)(Ctx + i) = *(uint4*)u;
}

// ---------------------------------------------------------------------------
// Kernel 3: output projection MFMA + bias + residual -> Resid fp32.
// grid (6, 64), block 256.
// ---------------------------------------------------------------------------
__global__ __launch_bounds__(256) void out_mfma_kernel(
    const __hip_bfloat16* __restrict__ Cb, const __hip_bfloat16* __restrict__ Wto,
    const float* __restrict__ bo, const float* __restrict__ X,
    float* __restrict__ Resid)
{
    const int n0 = blockIdx.x * 128;
    const int m0 = blockIdx.y * 128;

    const int t    = threadIdx.x;
    const int w    = t >> 6;
    const int lane = t & 63;
    const int col  = lane & 31;
    const int g    = lane >> 5;
    const int wm   = w & 1;
    const int wn   = w >> 1;

    __shared__ __hip_bfloat16 As[128][72];
    __shared__ __hip_bfloat16 Bs[128][72];

    f32x16 acc[2][2];
#pragma unroll
    for (int mt = 0; mt < 2; ++mt)
#pragma unroll
        for (int nt = 0; nt < 2; ++nt)
#pragma unroll
            for (int r = 0; r < 16; ++r) acc[mt][nt][r] = 0.f;

    for (int k0 = 0; k0 < HID; k0 += 64) {
        __syncthreads();
#pragma unroll
        for (int i = 0; i < 4; ++i) {
            const int idx = t + 256 * i;
            const int row = idx >> 3;
            const int c8  = (idx & 7) << 3;
            *(uint4*)&As[row][c8] = *(const uint4*)(Cb  + (size_t)(m0 + row) * HID + k0 + c8);
            *(uint4*)&Bs[row][c8] = *(const uint4*)(Wto + (size_t)(n0 + row) * HID + k0 + c8);
        }
        __syncthreads();
#pragma unroll
        for (int kh = 0; kh < 4; ++kh) {
            const int ko = 16 * kh + 8 * g;
            const bf16x8 a0 = *(const bf16x8*)&As[64 * wm + col][ko];
            const bf16x8 a1 = *(const bf16x8*)&As[64 * wm + 32 + col][ko];
            const bf16x8 b0 = *(const bf16x8*)&Bs[64 * wn + col][ko];
            const bf16x8 b1 = *(const bf16x8*)&Bs[64 * wn + 32 + col][ko];
            acc[0][0] = __builtin_amdgcn_mfma_f32_32x32x16_bf16(a0, b0, acc[0][0], 0, 0, 0);
            acc[0][1] = __builtin_amdgcn_mfma_f32_32x32x16_bf16(a0, b1, acc[0][1], 0, 0, 0);
            acc[1][0] = __builtin_amdgcn_mfma_f32_32x32x16_bf16(a1, b0, acc[1][0], 0, 0, 0);
            acc[1][1] = __builtin_amdgcn_mfma_f32_32x32x16_bf16(a1, b1, acc[1][1], 0, 0, 0);
        }
    }

#pragma unroll
    for (int mt = 0; mt < 2; ++mt)
#pragma unroll
        for (int nt = 0; nt < 2; ++nt) {
            const int n = n0 + 64 * wn + 32 * nt + col;
            const float bsv = bo[n];
#pragma unroll
            for (int r = 0; r < 16; ++r) {
                const int m = m0 + 64 * wm + 32 * mt + (r & 3) + 8 * (r >> 2) + 4 * g;
                Resid[(size_t)m * HID + n] = acc[mt][nt][r] + bsv + X[(size_t)m * HID + n];
            }
        }
}

// ---------------------------------------------------------------------------
// Kernel 4: LayerNorm.
// ---------------------------------------------------------------------------
__global__ __launch_bounds__(256) void ln_kernel(
    const float* __restrict__ Rin, const float* __restrict__ gamma,
    const float* __restrict__ beta, float* __restrict__ Out)
{
    const int row = blockIdx.x;
    const int t   = threadIdx.x;
    const float* __restrict__ x = Rin + (size_t)row * HID;

    const float v0 = x[t];
    const float v1 = x[t + 256];
    const float v2 = x[t + 512];
    float s  = v0 + v1 + v2;
    float s2 = v0 * v0 + v1 * v1 + v2 * v2;
#pragma unroll
    for (int off = 32; off; off >>= 1) {
        s  += __shfl_xor(s,  off, 64);
        s2 += __shfl_xor(s2, off, 64);
    }
    __shared__ float rs[4], rs2[4];
    const int w = t >> 6, lane = t & 63;
    if (lane == 0) { rs[w] = s; rs2[w] = s2; }
    __syncthreads();
    const float tot  = rs[0] + rs[1] + rs[2] + rs[3];
    const float tot2 = rs2[0] + rs2[1] + rs2[2] + rs2[3];
    const float mu   = tot * (1.0f / HID);
    const float var  = tot2 * (1.0f / HID) - mu * mu;
    const float rsig = rsqrtf(var + 1e-5f);

    float* __restrict__ y = Out + (size_t)row * HID;
    y[t]       = (v0 - mu) * rsig * gamma[t]       + beta[t];
    y[t + 256] = (v1 - mu) * rsig * gamma[t + 256] + beta[t + 256];
    y[t + 512] = (v2 - mu) * rsig * gamma[t + 512] + beta[t + 512];
}

// ---------------------------------------------------------------------------
extern "C" void kernel_launch(void* const* d_in, const int* in_sizes, int n_in,
                              void* d_out, int out_size, void* d_ws, size_t ws_size,
                              hipStream_t stream)
{
    const float* X     = (const float*)d_in[0];
    const float* mask  = (const float*)d_in[1];
    const float* Wq    = (const float*)d_in[2];
    const float* bq    = (const float*)d_in[3];
    const float* Wk    = (const float*)d_in[4];
    const float* bk    = (const float*)d_in[5];
    const float* Wv    = (const float*)d_in[6];
    const float* bv    = (const float*)d_in[7];
    const float* Wo    = (const float*)d_in[8];
    const float* bo    = (const float*)d_in[9];
    const float* gamma = (const float*)d_in[10];
    const float* beta  = (const float*)d_in[11];
    float* out = (float*)d_out;

    const size_t N = (size_t)MTOT * HID;        // 6,291,456 elements
    const size_t WTE = (size_t)4 * HID * HID;

    char* p = (char*)d_ws;
    __hip_bfloat16* Xb  = (__hip_bfloat16*)p;  p += 2 * N;
    __hip_bfloat16* Wt  = (__hip_bfloat16*)p;  p += 2 * WTE;
    __hip_bfloat16* Qw  = (__hip_bfloat16*)p;  p += 2 * N;
    __hip_bfloat16* Kw  = (__hip_bfloat16*)p;  p += 2 * N;
    __hip_bfloat16* Vtw = (__hip_bfloat16*)p;  p += 2 * N;
    char* opb = p;
    const size_t fixed = (size_t)(opb - (char*)d_ws);

    const size_t lpsz4 = 4 * (size_t)(BB * NHEADS) * SEQ * sizeof(float);
    const int KS = (ws_size >= fixed + 4 * 2 * N + lpsz4) ? 4 : 2;

    __hip_bfloat16* Op  = (__hip_bfloat16*)opb;          // KS*N bf16 partial O
    float* lpt = (float*)(opb + (size_t)KS * 2 * N);     // KS*24*SEQ fp32
    __hip_bfloat16* Ctxb = Xb;      // Xb dead after qkv
    float* Rd = (float*)Kw;         // Kw+Vtw dead after attn: exactly N fp32

    cast_x_kernel<<<(int)(N / 2048), 256, 0, stream>>>(X, Xb);
    pack_w_kernel<<<dim3(12, 12, 4), 256, 0, stream>>>(Wq, Wk, Wv, Wo, Wt);
    qkv_mfma_kernel<<<dim3(18, MTOT / 128), 256, 0, stream>>>(
        Xb, Wt, bq, bk, bv, Qw, Kw, Vtw);
    attn_kernel<<<dim3(SEQ / 256, BB * NHEADS, KS), 256, 0, stream>>>(
        Qw, Kw, Vtw, mask, Op, lpt);
    combine_kernel<<<(int)(N / 2048), 256, 0, stream>>>(Op, lpt, Ctxb, KS);
    out_mfma_kernel<<<dim3(6, MTOT / 128), 256, 0, stream>>>(
        Ctxb, Wt + (size_t)2304 * HID, bo, X, Rd);
    ln_kernel<<<MTOT, 256, 0, stream>>>(Rd, gamma, beta, out);
}

// Round 4
// 327.399 us; speedup vs baseline: 1.2147x; 1.0420x over previous
//
#include <hip/hip_runtime.h>
#include <hip/hip_bf16.h>

#define HID 768
#define NHEADS 12
#define HDIM 64
#define SEQ 4096
#define BB 2
#define MTOT (BB * SEQ)   // 8192 rows

typedef __attribute__((ext_vector_type(8))) short bf16x8;
typedef __attribute__((ext_vector_type(16))) float f32x16;

#define LOG2E 1.4426950408889634f

__device__ inline unsigned pack2bf(float a, float b) {
    __hip_bfloat162 h = __float22bfloat162_rn(float2{a, b});
    return *(unsigned*)&h;
}

// ---------------------------------------------------------------------------
// Kernel 0a: cast X fp32 -> bf16. grid 3072, block 256, 8 elems/thread.
// ---------------------------------------------------------------------------
__global__ __launch_bounds__(256) void cast_x_kernel(
    const float* __restrict__ X, __hip_bfloat16* __restrict__ Xb)
{
    const size_t i = ((size_t)blockIdx.x * 256 + threadIdx.x) * 8;
    const float4 x0 = *(const float4*)(X + i);
    const float4 x1 = *(const float4*)(X + i + 4);
    unsigned u[4];
    u[0] = pack2bf(x0.x, x0.y);
    u[1] = pack2bf(x0.z, x0.w);
    u[2] = pack2bf(x1.x, x1.y);
    u[3] = pack2bf(x1.z, x1.w);
    *(uint4*)(Xb + i) = *(uint4*)u;
}

// ---------------------------------------------------------------------------
// Kernel 0b: pack weights: W[in][out] fp32 -> Wt[out(global)][in] bf16.
// z=0..3 selects Wq,Wk,Wv,Wo; Wo at row offset 2304.
// ---------------------------------------------------------------------------
__global__ __launch_bounds__(256) void pack_w_kernel(
    const float* __restrict__ Wq, const float* __restrict__ Wk,
    const float* __restrict__ Wv, const float* __restrict__ Wo,
    __hip_bfloat16* __restrict__ Wt)
{
    const int z = blockIdx.z;
    const float* __restrict__ W = (z == 0) ? Wq : (z == 1) ? Wk : (z == 2) ? Wv : Wo;
    const int in0  = blockIdx.x * 64;
    const int out0 = blockIdx.y * 64;
    const int t = threadIdx.x;

    __shared__ float T[64][65];
#pragma unroll
    for (int i = 0; i < 4; ++i) {
        const int idx = t + 256 * i;
        const int row = idx >> 4;
        const int c4  = (idx & 15) << 2;
        const float4 v = *(const float4*)(W + (size_t)(in0 + row) * HID + out0 + c4);
        T[row][c4 + 0] = v.x; T[row][c4 + 1] = v.y;
        T[row][c4 + 2] = v.z; T[row][c4 + 3] = v.w;
    }
    __syncthreads();

    const int o  = t >> 2;
    const int cb = (t & 3) << 4;
    __hip_bfloat16 tmp[16];
#pragma unroll
    for (int k = 0; k < 16; ++k)
        tmp[k] = __float2bfloat16(T[cb + k][o]);
    __hip_bfloat16* __restrict__ dst =
        Wt + (size_t)(z * HID + out0 + o) * HID + in0 + cb;
    *(uint4*)(dst)     = *(uint4*)(&tmp[0]);
    *(uint4*)(dst + 8) = *(uint4*)(&tmp[8]);
}

// ---------------------------------------------------------------------------
// Kernel 1: fused QKV MFMA GEMM. Q,K -> bf16 [b,h,s,64]; V -> bf16 [b,h,64,s]
// (transposed in-epilogue via LDS). grid (18, 64), block 256, 128x128, BK=64.
// ---------------------------------------------------------------------------
__global__ __launch_bounds__(256) void qkv_mfma_kernel(
    const __hip_bfloat16* __restrict__ Xb, const __hip_bfloat16* __restrict__ Wt,
    const float* __restrict__ bq, const float* __restrict__ bk,
    const float* __restrict__ bv,
    __hip_bfloat16* __restrict__ Qo, __hip_bfloat16* __restrict__ Ko,
    __hip_bfloat16* __restrict__ Vo)
{
    const int nblk = blockIdx.x;          // 0..17
    const int z  = nblk / 6;              // 0=Q,1=K,2=V
    const int f0 = (nblk % 6) * 128;      // feature base within segment
    const int n0 = nblk * 128;            // row base in Wt
    const int m0 = blockIdx.y * 128;

    const float* __restrict__ bias = (z == 0) ? bq : (z == 1) ? bk : bv;

    const int t    = threadIdx.x;
    const int w    = t >> 6;
    const int lane = t & 63;
    const int col  = lane & 31;
    const int g    = lane >> 5;
    const int wm   = w & 1;
    const int wn   = w >> 1;

    __shared__ __hip_bfloat16 smem[2 * 128 * 72];   // As | Bs; Ts overlays both
    __hip_bfloat16 (*As)[72] = (__hip_bfloat16(*)[72])smem;
    __hip_bfloat16 (*Bs)[72] = (__hip_bfloat16(*)[72])(smem + 128 * 72);

    f32x16 acc[2][2];
#pragma unroll
    for (int mt = 0; mt < 2; ++mt)
#pragma unroll
        for (int nt = 0; nt < 2; ++nt)
#pragma unroll
            for (int r = 0; r < 16; ++r) acc[mt][nt][r] = 0.f;

    for (int k0 = 0; k0 < HID; k0 += 64) {
        __syncthreads();
#pragma unroll
        for (int i = 0; i < 4; ++i) {
            const int idx = t + 256 * i;     // 0..1023
            const int row = idx >> 3;        // 0..127
            const int c8  = (idx & 7) << 3;  // 0..56
            *(uint4*)&As[row][c8] = *(const uint4*)(Xb + (size_t)(m0 + row) * HID + k0 + c8);
            *(uint4*)&Bs[row][c8] = *(const uint4*)(Wt + (size_t)(n0 + row) * HID + k0 + c8);
        }
        __syncthreads();
#pragma unroll
        for (int kh = 0; kh < 4; ++kh) {
            const int ko = 16 * kh + 8 * g;
            const bf16x8 a0 = *(const bf16x8*)&As[64 * wm + col][ko];
            const bf16x8 a1 = *(const bf16x8*)&As[64 * wm + 32 + col][ko];
            const bf16x8 b0 = *(const bf16x8*)&Bs[64 * wn + col][ko];
            const bf16x8 b1 = *(const bf16x8*)&Bs[64 * wn + 32 + col][ko];
            acc[0][0] = __builtin_amdgcn_mfma_f32_32x32x16_bf16(a0, b0, acc[0][0], 0, 0, 0);
            acc[0][1] = __builtin_amdgcn_mfma_f32_32x32x16_bf16(a0, b1, acc[0][1], 0, 0, 0);
            acc[1][0] = __builtin_amdgcn_mfma_f32_32x32x16_bf16(a1, b0, acc[1][0], 0, 0, 0);
            acc[1][1] = __builtin_amdgcn_mfma_f32_32x32x16_bf16(a1, b1, acc[1][1], 0, 0, 0);
        }
    }

    if (z < 2) {
        __hip_bfloat16* __restrict__ Out = (z == 0) ? Qo : Ko;
        const int h = (f0 >> 6) + wn;
#pragma unroll
        for (int mt = 0; mt < 2; ++mt)
#pragma unroll
            for (int nt = 0; nt < 2; ++nt) {
                const int d = 32 * nt + col;
                const float bsv = bias[f0 + 64 * wn + d];
#pragma unroll
                for (int r = 0; r < 16; ++r) {
                    const int m = m0 + 64 * wm + 32 * mt + (r & 3) + 8 * (r >> 2) + 4 * g;
                    const int b = m >> 12;
                    const int s = m & (SEQ - 1);
                    Out[(((size_t)(b * NHEADS + h)) * SEQ + s) * HDIM + d] =
                        __float2bfloat16(acc[mt][nt][r] + bsv);
                }
            }
    } else {
        // V: transpose 128x128 tile via LDS, write Vt [bh][d][s]
        __syncthreads();   // K-loop LDS reads done before overlay
        __hip_bfloat16 (*Ts)[136] = (__hip_bfloat16(*)[136])smem;  // 34816 B
#pragma unroll
        for (int mt = 0; mt < 2; ++mt)
#pragma unroll
            for (int nt = 0; nt < 2; ++nt) {
                const int nloc = 64 * wn + 32 * nt + col;
                const float bsv = bias[f0 + nloc];
#pragma unroll
                for (int rg = 0; rg < 4; ++rg) {
                    const int mbase = 64 * wm + 32 * mt + 8 * rg + 4 * g;
                    unsigned pu[2];
                    pu[0] = pack2bf(acc[mt][nt][4 * rg + 0] + bsv,
                                    acc[mt][nt][4 * rg + 1] + bsv);
                    pu[1] = pack2bf(acc[mt][nt][4 * rg + 2] + bsv,
                                    acc[mt][nt][4 * rg + 3] + bsv);
                    *(uint2*)&Ts[nloc][mbase] = *(uint2*)pu;
                }
            }
        __syncthreads();
        const int nloc = t >> 1;
        const int half = t & 1;
        const int hh = (f0 >> 6) + (nloc >> 6);
        const int d  = nloc & 63;
        const int bb = m0 >> 12;
        const int s0 = m0 & (SEQ - 1);
        __hip_bfloat16* __restrict__ dst =
            Vo + (((size_t)(bb * NHEADS + hh)) * HDIM + d) * SEQ + s0 + 64 * half;
        const __hip_bfloat16* srcp = &Ts[nloc][64 * half];
#pragma unroll
        for (int j = 0; j < 8; ++j)
            *(uint4*)(dst + 8 * j) = *(const uint4*)(srcp + 8 * j);
    }
}

// ---------------------------------------------------------------------------
// Kernel 2: MFMA flash attention (S^T-swap, K-split). exp2-folded softmax.
// REGISTER BUDGET (rounds 1-2): (256,2) budget is 256 regs/wave; working set
// ~248. No live-across-compute registers allowed (T14 reg-staging spilled:
// WRITE_SIZE 50.7->108 MB). Round-3 lesson: setprio around individual MFMA
// pairs (16 toggles/tile) acts as scheduling fences -> -10us; removed.
// ROUND-4 STRUCTURE: T3 "minimum 2-phase" with global_load_lds (zero-VGPR
// async staging, m230-V0 pattern):
//   prologue: STAGE(buf0); barrier;
//   loop:     STAGE(buf^1, next tile); compute(buf); barrier (compiler emits
//             vmcnt(0) drain there == the intended wait); swap.
// One barrier per tile (was 2), staging latency hidden under compute, no
// staging VGPRs, no ds_write VALU. global_load_lds writes linearly
// (wave-uniform base + lane*16, m104/m173), so LDS is unpadded [64][64] and
// bank conflicts are broken by a 16B-chunk XOR swizzle applied BOTH sides
// (rule #21): LDS[r][c'] holds global chunk c'^(r&7); reads use
// chunk ((2kh+g)^(row&7)). Read-side banks: 8 distinct 4-bank starts x 4
// lanes each per half-wave -> balanced (expect SQ_LDS_BANK_CONFLICT ~ 0).
// K-loop 2-unrolled so the buffer index is compile-time constant.
// Kept from round 3: whole-span madd in LDS, permlane32_swap P-transform.
// ---------------------------------------------------------------------------
typedef __attribute__((ext_vector_type(2))) unsigned uswap2;

__global__ __launch_bounds__(256, 2) void attn_kernel(
    const __hip_bfloat16* __restrict__ Qb, const __hip_bfloat16* __restrict__ Kb,
    const __hip_bfloat16* __restrict__ Vt, const float* __restrict__ mask,
    __hip_bfloat16* __restrict__ Op, float* __restrict__ lp)
{
    const int bh = blockIdx.y;
    const int b  = bh / NHEADS;
    const int h  = bh - b * NHEADS;
    const int kspan = SEQ / gridDim.z;
    const int kbeg  = blockIdx.z * kspan;

    const int t    = threadIdx.x;
    const int w    = t >> 6;
    const int lane = t & 63;
    const int col  = lane & 31;
    const int g    = lane >> 5;
    const int qw   = blockIdx.x * 256 + 64 * w;

    __shared__ __hip_bfloat16 Ksb[2][64][64];   // 16 KiB, unpadded (DMA dest)
    __shared__ __hip_bfloat16 Vsb[2][64][64];   // 16 KiB
    __shared__ float madd[2048];                // whole kspan, premult log2(e)

    const __hip_bfloat16* __restrict__ Qh = Qb + (size_t)bh * SEQ * HDIM;
    const __hip_bfloat16* __restrict__ Kh = Kb + (size_t)bh * SEQ * HDIM;
    const __hip_bfloat16* __restrict__ Vh = Vt + (size_t)bh * HDIM * SEQ;

    // whole-span additive mask, computed once (visible after prologue barrier)
    for (int j = t; j < kspan; j += 256)
        madd[j] = (1.0f - mask[b * SEQ + kbeg + j]) * (-10000.0f * LOG2E);

    // staging geometry: thread t covers LDS 16B-chunk n = t (+256 for issue 1)
    // row r = n>>3 (issue1: +32, same r&7), LDS chunk c' = t&7; global source
    // chunk = c' ^ (r&7) (inverse swizzle at the source, rule #21).
    const int r0  = t >> 3;                          // 0..31
    const int csw = (((t & 7) ^ (r0 & 7)) << 3);     // swizzled src chunk (elems)

#define STAGE(BUF, KT) do {                                                        \
    const __hip_bfloat16* gk0_ = Kh + (size_t)((KT) + r0) * HDIM + csw;            \
    const __hip_bfloat16* gk1_ = Kh + (size_t)((KT) + r0 + 32) * HDIM + csw;       \
    const __hip_bfloat16* gv0_ = Vh + (size_t)r0 * SEQ + (KT) + csw;               \
    const __hip_bfloat16* gv1_ = Vh + (size_t)(r0 + 32) * SEQ + (KT) + csw;        \
    __hip_bfloat16* lk_ = &Ksb[BUF][0][0] + w * 512;                               \
    __hip_bfloat16* lv_ = &Vsb[BUF][0][0] + w * 512;                               \
    __builtin_amdgcn_global_load_lds(                                              \
        (const __attribute__((address_space(1))) unsigned*)gk0_,                   \
        (__attribute__((address_space(3))) unsigned*)lk_, 16, 0, 0);               \
    __builtin_amdgcn_global_load_lds(                                              \
        (const __attribute__((address_space(1))) unsigned*)gk1_,                   \
        (__attribute__((address_space(3))) unsigned*)(lk_ + 2048), 16, 0, 0);      \
    __builtin_amdgcn_global_load_lds(                                              \
        (const __attribute__((address_space(1))) unsigned*)gv0_,                   \
        (__attribute__((address_space(3))) unsigned*)lv_, 16, 0, 0);               \
    __builtin_amdgcn_global_load_lds(                                              \
        (const __attribute__((address_space(1))) unsigned*)gv1_,                   \
        (__attribute__((address_space(3))) unsigned*)(lv_ + 2048), 16, 0, 0);      \
} while (0)

    bf16x8 bq[2][4];
#pragma unroll
    for (int mt = 0; mt < 2; ++mt)
#pragma unroll
        for (int kh = 0; kh < 4; ++kh)
            bq[mt][kh] = *(const bf16x8*)(Qh + (size_t)(qw + 32 * mt + col) * HDIM
                                          + 16 * kh + 8 * g);

    f32x16 O[2][2];
    float lac[2] = {0.f, 0.f};
#pragma unroll
    for (int mt = 0; mt < 2; ++mt)
#pragma unroll
        for (int dt = 0; dt < 2; ++dt)
#pragma unroll
            for (int r = 0; r < 16; ++r) O[mt][dt][r] = 0.f;

    const float kscale = 0.125f * LOG2E;

// one tile: QK^T (swapped) -> softmax exp+pack -> permlane transform -> PV.
// BUF is a literal; all LDS offsets compile-time within the unrolled body.
#define ATTN_TILE(BUF, KT0) do {                                                   \
    f32x16 St[2][2];                                                               \
    _Pragma("unroll")                                                              \
    for (int mt = 0; mt < 2; ++mt)                                                 \
        _Pragma("unroll")                                                          \
        for (int nt = 0; nt < 2; ++nt)                                             \
            _Pragma("unroll")                                                      \
            for (int r = 0; r < 16; ++r) St[mt][nt][r] = 0.f;                      \
    _Pragma("unroll")                                                              \
    for (int kh = 0; kh < 4; ++kh) {                                               \
        const int sc = ((2 * kh + g) ^ (col & 7)) << 3;                            \
        const bf16x8 ak0 = *(const bf16x8*)&Ksb[BUF][col][sc];                     \
        const bf16x8 ak1 = *(const bf16x8*)&Ksb[BUF][32 + col][sc];                \
        St[0][0] = __builtin_amdgcn_mfma_f32_32x32x16_bf16(ak0, bq[0][kh], St[0][0], 0, 0, 0); \
        St[1][0] = __builtin_amdgcn_mfma_f32_32x32x16_bf16(ak0, bq[1][kh], St[1][0], 0, 0, 0); \
        St[0][1] = __builtin_amdgcn_mfma_f32_32x32x16_bf16(ak1, bq[0][kh], St[0][1], 0, 0, 0); \
        St[1][1] = __builtin_amdgcn_mfma_f32_32x32x16_bf16(ak1, bq[1][kh], St[1][1], 0, 0, 0); \
    }                                                                              \
    _Pragma("unroll")                                                              \
    for (int mt = 0; mt < 2; ++mt) {                                               \
        unsigned g4x[2][4], g4y[2][4];                                             \
        _Pragma("unroll")                                                          \
        for (int nt = 0; nt < 2; ++nt) {                                           \
            _Pragma("unroll")                                                      \
            for (int b4 = 0; b4 < 4; ++b4) {                                       \
                const float4 mm = *(const float4*)&madd[(KT0) + 32 * nt + 8 * b4 + 4 * g]; \
                const float p0 = __builtin_amdgcn_exp2f(fmaf(St[mt][nt][4 * b4 + 0], kscale, mm.x)); \
                const float p1 = __builtin_amdgcn_exp2f(fmaf(St[mt][nt][4 * b4 + 1], kscale, mm.y)); \
                const float p2 = __builtin_amdgcn_exp2f(fmaf(St[mt][nt][4 * b4 + 2], kscale, mm.z)); \
                const float p3 = __builtin_amdgcn_exp2f(fmaf(St[mt][nt][4 * b4 + 3], kscale, mm.w)); \
                lac[mt] += (p0 + p1) + (p2 + p3);                                  \
                g4x[nt][b4] = pack2bf(p0, p1);                                     \
                g4y[nt][b4] = pack2bf(p2, p3);                                     \
            }                                                                      \
        }                                                                          \
        _Pragma("unroll")                                                          \
        for (int kh = 0; kh < 4; ++kh) {                                           \
            const int nt  = kh >> 1;                                               \
            const int khl = kh & 1;                                                \
            union { unsigned u[4]; bf16x8 v; } au;                                 \
            ATTN_PTRANS(au, g4x[nt][2 * khl], g4x[nt][2 * khl + 1],                \
                            g4y[nt][2 * khl], g4y[nt][2 * khl + 1]);               \
            const int sc = ((2 * kh + g) ^ (col & 7)) << 3;                        \
            const bf16x8 bv0 = *(const bf16x8*)&Vsb[BUF][col][sc];                 \
            const bf16x8 bv1 = *(const bf16x8*)&Vsb[BUF][32 + col][sc];            \
            O[mt][0] = __builtin_amdgcn_mfma_f32_32x32x16_bf16(au.v, bv0, O[mt][0], 0, 0, 0); \
            O[mt][1] = __builtin_amdgcn_mfma_f32_32x32x16_bf16(au.v, bv1, O[mt][1], 0, 0, 0); \
        }                                                                          \
    }                                                                              \
} while (0)

#if __has_builtin(__builtin_amdgcn_permlane32_swap)
    // result[0] = l<32 ? lo[l] : hi[l-32]; result[1] = l<32 ? lo[l+32] : hi[l]
    // == exactly A-frag words u0/u2 (verified rounds 1-3, absmax unchanged).
#define ATTN_PTRANS(au, lox, hix, loy, hiy) do {                                   \
    uswap2 sx_ = __builtin_amdgcn_permlane32_swap((lox), (hix), false, false);     \
    uswap2 sy_ = __builtin_amdgcn_permlane32_swap((loy), (hiy), false, false);     \
    au.u[0] = sx_[0]; au.u[1] = sy_[0]; au.u[2] = sx_[1]; au.u[3] = sy_[1];        \
} while (0)
#else
#define ATTN_PTRANS(au, lox, hix, loy, hiy) do {                                   \
    const unsigned sxv_ = g ? (lox) : (hix);                                       \
    const unsigned syv_ = g ? (loy) : (hiy);                                       \
    const unsigned rx_ = (unsigned)__shfl_xor((int)sxv_, 32, 64);                  \
    const unsigned ry_ = (unsigned)__shfl_xor((int)syv_, 32, 64);                  \
    if (g) { au.u[0] = rx_;   au.u[1] = ry_;   au.u[2] = (hix); au.u[3] = (hiy); } \
    else   { au.u[0] = (lox); au.u[1] = (loy); au.u[2] = rx_;   au.u[3] = ry_;  }  \
} while (0)
#endif

    // ---- 2-phase pipelined K-loop (T3-lite), 2 tiles per iteration ----
    STAGE(0, kbeg);
    __syncthreads();                       // prologue drain (vmcnt0 + madd)

    for (int kt0 = 0; kt0 < kspan; kt0 += 128) {
        STAGE(1, kbeg + kt0 + 64);         // always valid: kt0+64 < kspan
        ATTN_TILE(0, kt0);
        __syncthreads();                   // drains my DMA into buf1; all waves done with buf0
        if (kt0 + 128 < kspan) STAGE(0, kbeg + kt0 + 128);
        ATTN_TILE(1, kt0 + 64);
        __syncthreads();                   // drains DMA into buf0; all waves done with buf1
    }
#undef STAGE
#undef ATTN_TILE
#undef ATTN_PTRANS

    const size_t opbase = (size_t)blockIdx.z * ((size_t)MTOT * HID);
#pragma unroll
    for (int mt = 0; mt < 2; ++mt) {
        const float l = lac[mt] + __shfl_xor(lac[mt], 32, 64);
        if (g == 0)
            lp[((size_t)blockIdx.z * (BB * NHEADS) + bh) * SEQ + qw + 32 * mt + col] = l;
#pragma unroll
        for (int dt = 0; dt < 2; ++dt)
#pragma unroll
            for (int r = 0; r < 16; ++r) {
                const int q = qw + 32 * mt + (r & 3) + 8 * (r >> 2) + 4 * g;
                const int d = 32 * dt + col;
                Op[opbase + ((size_t)b * SEQ + q) * HID + h * HDIM + d] =
                    __float2bfloat16(O[mt][dt][r]);
            }
    }
}

// ---------------------------------------------------------------------------
// Kernel 2b: combine K-split partials -> Ctx bf16. 8 elems/thread.
// ---------------------------------------------------------------------------
__global__ __launch_bounds__(256) void combine_kernel(
    const __hip_bfloat16* __restrict__ Op, const float* __restrict__ lp,
    __hip_bfloat16* __restrict__ Ctx, int KS)
{
    const size_t i = ((size_t)blockIdx.x * 256 + threadIdx.x) * 8;
    const int n   = (int)(i % HID);
    const int row = (int)(i / HID);
    const int h = n >> 6;
    const int b = row >> 12;
    const int q = row & (SEQ - 1);
    const int bh = b * NHEADS + h;

    float denom = 0.f;
    float o[8] = {};
    for (int kz = 0; kz < KS; ++kz) {
        denom += lp[((size_t)kz * (BB * NHEADS) + bh) * SEQ + q];
        uint4 u = *(const uint4*)(Op + (size_t)kz * ((size_t)MTOT * HID) + i);
        const __hip_bfloat16* e = (const __hip_bfloat16*)&u;
#pragma unroll
        for (int j = 0; j < 8; ++j) o[j] += __bfloat162float(e[j]);
    }
    const float inv = 1.0f / denom;
    unsigned u[4];
#pragma unroll
    for (int j = 0; j < 4; ++j)
        u[j] = pack2bf(o[2 * j] * inv, o[2 * j + 1] * inv);
    *(uint4*)(Ctx + i) = *(uint4*)u;
}

// ---------------------------------------------------------------------------
// Kernel 3: output projection MFMA + bias + residual -> Resid fp32.
// grid (6, 64), block 256.
// ---------------------------------------------------------------------------
__global__ __launch_bounds__(256) void out_mfma_kernel(
    const __hip_bfloat16* __restrict__ Cb, const __hip_bfloat16* __restrict__ Wto,
    const float* __restrict__ bo, const float* __restrict__ X,
    float* __restrict__ Resid)
{
    const int n0 = blockIdx.x * 128;
    const int m0 = blockIdx.y * 128;

    const int t    = threadIdx.x;
    const int w    = t >> 6;
    const int lane = t & 63;
    const int col  = lane & 31;
    const int g    = lane >> 5;
    const int wm   = w & 1;
    const int wn   = w >> 1;

    __shared__ __hip_bfloat16 As[128][72];
    __shared__ __hip_bfloat16 Bs[128][72];

    f32x16 acc[2][2];
#pragma unroll
    for (int mt = 0; mt < 2; ++mt)
#pragma unroll
        for (int nt = 0; nt < 2; ++nt)
#pragma unroll
            for (int r = 0; r < 16; ++r) acc[mt][nt][r] = 0.f;

    for (int k0 = 0; k0 < HID; k0 += 64) {
        __syncthreads();
#pragma unroll
        for (int i = 0; i < 4; ++i) {
            const int idx = t + 256 * i;
            const int row = idx >> 3;
            const int c8  = (idx & 7) << 3;
            *(uint4*)&As[row][c8] = *(const uint4*)(Cb  + (size_t)(m0 + row) * HID + k0 + c8);
            *(uint4*)&Bs[row][c8] = *(const uint4*)(Wto + (size_t)(n0 + row) * HID + k0 + c8);
        }
        __syncthreads();
#pragma unroll
        for (int kh = 0; kh < 4; ++kh) {
            const int ko = 16 * kh + 8 * g;
            const bf16x8 a0 = *(const bf16x8*)&As[64 * wm + col][ko];
            const bf16x8 a1 = *(const bf16x8*)&As[64 * wm + 32 + col][ko];
            const bf16x8 b0 = *(const bf16x8*)&Bs[64 * wn + col][ko];
            const bf16x8 b1 = *(const bf16x8*)&Bs[64 * wn + 32 + col][ko];
            acc[0][0] = __builtin_amdgcn_mfma_f32_32x32x16_bf16(a0, b0, acc[0][0], 0, 0, 0);
            acc[0][1] = __builtin_amdgcn_mfma_f32_32x32x16_bf16(a0, b1, acc[0][1], 0, 0, 0);
            acc[1][0] = __builtin_amdgcn_mfma_f32_32x32x16_bf16(a1, b0, acc[1][0], 0, 0, 0);
            acc[1][1] = __builtin_amdgcn_mfma_f32_32x32x16_bf16(a1, b1, acc[1][1], 0, 0, 0);
        }
    }

#pragma unroll
    for (int mt = 0; mt < 2; ++mt)
#pragma unroll
        for (int nt = 0; nt < 2; ++nt) {
            const int n = n0 + 64 * wn + 32 * nt + col;
            const float bsv = bo[n];
#pragma unroll
            for (int r = 0; r < 16; ++r) {
                const int m = m0 + 64 * wm + 32 * mt + (r & 3) + 8 * (r >> 2) + 4 * g;
                Resid[(size_t)m * HID + n] = acc[mt][nt][r] + bsv + X[(size_t)m * HID + n];
            }
        }
}

// ---------------------------------------------------------------------------
// Kernel 4: LayerNorm.
// ---------------------------------------------------------------------------
__global__ __launch_bounds__(256) void ln_kernel(
    const float* __restrict__ Rin, const float* __restrict__ gamma,
    const float* __restrict__ beta, float* __restrict__ Out)
{
    const int row = blockIdx.x;
    const int t   = threadIdx.x;
    const float* __restrict__ x = Rin + (size_t)row * HID;

    const float v0 = x[t];
    const float v1 = x[t + 256];
    const float v2 = x[t + 512];
    float s  = v0 + v1 + v2;
    float s2 = v0 * v0 + v1 * v1 + v2 * v2;
#pragma unroll
    for (int off = 32; off; off >>= 1) {
        s  += __shfl_xor(s,  off, 64);
        s2 += __shfl_xor(s2, off, 64);
    }
    __shared__ float rs[4], rs2[4];
    const int w = t >> 6, lane = t & 63;
    if (lane == 0) { rs[w] = s; rs2[w] = s2; }
    __syncthreads();
    const float tot  = rs[0] + rs[1] + rs[2] + rs[3];
    const float tot2 = rs2[0] + rs2[1] + rs2[2] + rs2[3];
    const float mu   = tot * (1.0f / HID);
    const float var  = tot2 * (1.0f / HID) - mu * mu;
    const float rsig = rsqrtf(var + 1e-5f);

    float* __restrict__ y = Out + (size_t)row * HID;
    y[t]       = (v0 - mu) * rsig * gamma[t]       + beta[t];
    y[t + 256] = (v1 - mu) * rsig * gamma[t + 256] + beta[t + 256];
    y[t + 512] = (v2 - mu) * rsig * gamma[t + 512] + beta[t + 512];
}

// ---------------------------------------------------------------------------
extern "C" void kernel_launch(void* const* d_in, const int* in_sizes, int n_in,
                              void* d_out, int out_size, void* d_ws, size_t ws_size,
                              hipStream_t stream)
{
    const float* X     = (const float*)d_in[0];
    const float* mask  = (const float*)d_in[1];
    const float* Wq    = (const float*)d_in[2];
    const float* bq    = (const float*)d_in[3];
    const float* Wk    = (const float*)d_in[4];
    const float* bk    = (const float*)d_in[5];
    const float* Wv    = (const float*)d_in[6];
    const float* bv    = (const float*)d_in[7];
    const float* Wo    = (const float*)d_in[8];
    const float* bo    = (const float*)d_in[9];
    const float* gamma = (const float*)d_in[10];
    const float* beta  = (const float*)d_in[11];
    float* out = (float*)d_out;

    const size_t N = (size_t)MTOT * HID;        // 6,291,456 elements
    const size_t WTE = (size_t)4 * HID * HID;

    char* p = (char*)d_ws;
    __hip_bfloat16* Xb  = (__hip_bfloat16*)p;  p += 2 * N;
    __hip_bfloat16* Wt  = (__hip_bfloat16*)p;  p += 2 * WTE;
    __hip_bfloat16* Qw  = (__hip_bfloat16*)p;  p += 2 * N;
    __hip_bfloat16* Kw  = (__hip_bfloat16*)p;  p += 2 * N;
    __hip_bfloat16* Vtw = (__hip_bfloat16*)p;  p += 2 * N;
    char* opb = p;
    const size_t fixed = (size_t)(opb - (char*)d_ws);

    const size_t lpsz4 = 4 * (size_t)(BB * NHEADS) * SEQ * sizeof(float);
    const int KS = (ws_size >= fixed + 4 * 2 * N + lpsz4) ? 4 : 2;

    __hip_bfloat16* Op  = (__hip_bfloat16*)opb;          // KS*N bf16 partial O
    float* lpt = (float*)(opb + (size_t)KS * 2 * N);     // KS*24*SEQ fp32
    __hip_bfloat16* Ctxb = Xb;      // Xb dead after qkv
    float* Rd = (float*)Kw;         // Kw+Vtw dead after attn: exactly N fp32

    cast_x_kernel<<<(int)(N / 2048), 256, 0, stream>>>(X, Xb);
    pack_w_kernel<<<dim3(12, 12, 4), 256, 0, stream>>>(Wq, Wk, Wv, Wo, Wt);
    qkv_mfma_kernel<<<dim3(18, MTOT / 128), 256, 0, stream>>>(
        Xb, Wt, bq, bk, bv, Qw, Kw, Vtw);
    attn_kernel<<<dim3(SEQ / 256, BB * NHEADS, KS), 256, 0, stream>>>(
        Qw, Kw, Vtw, mask, Op, lpt);
    combine_kernel<<<(int)(N / 2048), 256, 0, stream>>>(Op, lpt, Ctxb, KS);
    out_mfma_kernel<<<dim3(6, MTOT / 128), 256, 0, stream>>>(
        Ctxb, Wt + (size_t)2304 * HID, bo, X, Rd);
    ln_kernel<<<MTOT, 256, 0, stream>>>(Rd, gamma, beta, out);
}